// Round 1
// 386.537 us; speedup vs baseline: 1.2427x; 1.2427x over previous
//
#include <hip/hip_runtime.h>

typedef __bf16 bf16;
typedef _Float16 f16;
typedef f16  f16x8  __attribute__((ext_vector_type(8)));
typedef f16  f16x4v __attribute__((ext_vector_type(4)));
typedef float f32x4 __attribute__((ext_vector_type(4)));

#define MFMA_F16(a,b,c) __builtin_amdgcn_mfma_f32_16x16x32_f16((a),(b),(c),0,0,0)

#define NWIN 512
#define NTOK 64
#define NH 8
#define HD 32
#define DIM 256

// Sb row stride (f16 units). 1544*2 = 3088 B ≡ 16 mod 128 -> consecutive m-lanes
// step one 16B bank-slot per row; breaks the 16-way ds_read_b128 conflict that
// the 1536 (3072 B ≡ 0 mod 128) stride caused. Must stay a multiple of 8 f16
// (16 B) for aligned f16x8 reads. 16*1544*2 = 49408 B <= 50176 B sm buffer.
#define SB_STRIDE 1544

// load 8 consecutive fp32, round to f16x8
__device__ __forceinline__ f16x8 ld_f16x8(const float* __restrict__ p) {
  f32x4 a = *(const f32x4*)p;
  f32x4 b = *(const f32x4*)(p + 4);
  f16x8 r;
  r[0] = (f16)a[0]; r[1] = (f16)a[1]; r[2] = (f16)a[2]; r[3] = (f16)a[3];
  r[4] = (f16)b[0]; r[5] = (f16)b[1]; r[6] = (f16)b[2]; r[7] = (f16)b[3];
  return r;
}

// ---------------- prep: CPB MLP -> 16*sigmoid(bias) table [2][225][8] f32 ----
// R5: was grid=2 (2 CUs busy, serial 512-iter latency chain, ~187 us).
// Now grid = 2 views x 225 entries = 450 blocks; u-loop split across 256
// threads with wave shfl reduce + LDS cross-wave reduce. Expected < 10 us.
__global__ __launch_bounds__(256) void prep_cpb(
    const float* __restrict__ w1a, const float* __restrict__ b1a,
    const float* __restrict__ w2a,
    const float* __restrict__ w1b, const float* __restrict__ b1b,
    const float* __restrict__ w2b,
    float* __restrict__ sg16) {
  const int view = blockIdx.x / 225;
  const int e    = blockIdx.x % 225;
  const float* __restrict__ w1 = view ? w1b : w1a;
  const float* __restrict__ b1 = view ? b1b : b1a;
  const float* __restrict__ w2 = view ? w2b : w2a;
  const int t = threadIdx.x;
  const int i = e / 15, j = e % 15;
  const float vi = 8.0f * (float)(i - 7) * (1.0f / 7.0f);
  const float vj = 8.0f * (float)(j - 7) * (1.0f / 7.0f);
  const float in0 = copysignf(log2f(fabsf(vi) + 1.0f) * (1.0f / 3.0f), vi);
  const float in1 = copysignf(log2f(fabsf(vj) + 1.0f) * (1.0f / 3.0f), vj);
  float acc[8] = {0.f,0.f,0.f,0.f,0.f,0.f,0.f,0.f};
#pragma unroll
  for (int uu = 0; uu < 2; ++uu) {
    const int u = t + uu * 256;
    float hv = fmaxf(w1[2*u] * in0 + w1[2*u+1] * in1 + b1[u], 0.0f);
#pragma unroll
    for (int hh = 0; hh < 8; ++hh) acc[hh] += w2[hh*512 + u] * hv;
  }
  // reduce across the 64-lane wave
#pragma unroll
  for (int off = 32; off >= 1; off >>= 1)
#pragma unroll
    for (int hh = 0; hh < 8; ++hh) acc[hh] += __shfl_xor(acc[hh], off, 64);
  __shared__ float red[4][8];
  if ((t & 63) == 0) {
#pragma unroll
    for (int hh = 0; hh < 8; ++hh) red[t >> 6][hh] = acc[hh];
  }
  __syncthreads();
  if (t < 8) {
    float s = red[0][t] + red[1][t] + red[2][t] + red[3][t];
    sg16[(view * 225 + e) * 8 + t] = 16.0f / (1.0f + __expf(-s));
  }
}

// ---------------- fused: per-window (both views) QKV + attention + proj ------
__global__ __launch_bounds__(512, 2) void fused_attn(
    const float* __restrict__ x1, const float* __restrict__ x2,
    const float* __restrict__ qkvw1, const float* __restrict__ qb1, const float* __restrict__ vb1,
    const float* __restrict__ qkvw2, const float* __restrict__ qb2, const float* __restrict__ vb2,
    const float* __restrict__ pcw1, const float* __restrict__ pcb1, const float* __restrict__ ls1,
    const float* __restrict__ pcw2, const float* __restrict__ pcb2, const float* __restrict__ ls2,
    const float* __restrict__ pw1, const float* __restrict__ pb1,
    const float* __restrict__ pw2, const float* __restrict__ pb2,
    const float* __restrict__ sg16,
    float* __restrict__ outp) {
  const int win = blockIdx.x;
  const int tid = threadIdx.x;
  const int lane = tid & 63, h = tid >> 6;
  const int quad = lane >> 4, m = lane & 15;

  __shared__ __align__(16) char sm[50176];
  __shared__ float sTbl[1800];
  f16* bufX = (f16*)sm;
  f16* bufO = (f16*)(sm + 9216);
  f16* Sb   = (f16*)sm;
  f16* preB = (f16*)sm;

  const f32x4 z4 = {0.f, 0.f, 0.f, 0.f};
  f16x8 aqF[2][4], kfF[2][4], bvF[2][2][2];

  // ================= QKV GEMMs, both views =================
#pragma unroll
  for (int view = 0; view < 2; ++view) {
    const float* __restrict__ xv = (view ? x2 : x1) + (size_t)win * (NTOK * DIM);
    const float* __restrict__ W  = view ? qkvw2 : qkvw1;
    const float* __restrict__ qb = view ? qb2 : qb1;
    const float* __restrict__ vb = view ? vb2 : vb1;
    for (int sec = 0; sec < 3; ++sec) {
      f32x4 acc0[4], acc1[4];
#pragma unroll
      for (int t = 0; t < 4; ++t) { acc0[t] = z4; acc1[t] = z4; }
      for (int qtr = 0; qtr < 4; ++qtr) {
        __syncthreads();   // bufX safe to overwrite
        {
          int n = tid >> 3, col = (tid & 7) * 8;
          *(f16x8*)(bufX + n * 72 + col) = ld_f16x8(xv + n * 256 + qtr * 64 + col);
        }
        __syncthreads();   // bufX ready
        f16x8 a0[2], a1[2];
        const float* wb = W + (size_t)(sec * 256 + h * 32) * 256 + qtr * 64 + quad * 8;
#pragma unroll
        for (int ks = 0; ks < 2; ++ks) {
          a0[ks] = ld_f16x8(wb + (size_t)m * 256 + ks * 32);
          a1[ks] = ld_f16x8(wb + (size_t)(16 + m) * 256 + ks * 32);
        }
#pragma unroll
        for (int tt = 0; tt < 4; ++tt) {
#pragma unroll
          for (int ks = 0; ks < 2; ++ks) {
            f16x8 bfr = *(const f16x8*)(bufX + (tt * 16 + m) * 72 + ks * 32 + quad * 8);
            acc0[tt] = MFMA_F16(a0[ks], bfr, acc0[tt]);
            acc1[tt] = MFMA_F16(a1[ks], bfr, acc1[tt]);
          }
        }
      }
      // epilogue: bias, (l2norm q/k), write f16 [token][hd] to own head region
      float bs0[4], bs1[4];
#pragma unroll
      for (int r = 0; r < 4; ++r) {
        int c0 = h * 32 + quad * 4 + r;
        bs0[r] = (sec == 0) ? qb[c0] : (sec == 2 ? vb[c0] : 0.f);
        bs1[r] = (sec == 0) ? qb[c0 + 16] : (sec == 2 ? vb[c0 + 16] : 0.f);
      }
      f16* oh = bufO + h * 2560;
#pragma unroll
      for (int tt = 0; tt < 4; ++tt) {
        float v0[4], v1[4];
#pragma unroll
        for (int r = 0; r < 4; ++r) { v0[r] = acc0[tt][r] + bs0[r]; v1[r] = acc1[tt][r] + bs1[r]; }
        if (sec < 2) {
          float ss = 0.f;
#pragma unroll
          for (int r = 0; r < 4; ++r) ss += v0[r] * v0[r] + v1[r] * v1[r];
          ss += __shfl_xor(ss, 16, 64);
          ss += __shfl_xor(ss, 32, 64);
          float s = 1.0f / fmaxf(sqrtf(ss), 1e-12f);
#pragma unroll
          for (int r = 0; r < 4; ++r) { v0[r] *= s; v1[r] *= s; }
        }
        const int n = tt * 16 + m;
        f16x4v p0, p1;
#pragma unroll
        for (int r = 0; r < 4; ++r) { p0[r] = (f16)v0[r]; p1[r] = (f16)v1[r]; }
        *(f16x4v*)(oh + n * 40 + quad * 4)      = p0;
        *(f16x4v*)(oh + n * 40 + 16 + quad * 4) = p1;
      }
      __syncthreads();   // bufO ready
      if (sec == 0) {
#pragma unroll
        for (int rt = 0; rt < 4; ++rt)
          aqF[view][rt] = *(const f16x8*)(oh + (rt * 16 + m) * 40 + quad * 8);
      } else if (sec == 1) {
#pragma unroll
        for (int ct = 0; ct < 4; ++ct)
          kfF[view][ct] = *(const f16x8*)(oh + (ct * 16 + m) * 40 + quad * 8);
      } else {
#pragma unroll
        for (int nt = 0; nt < 2; ++nt)
#pragma unroll
          for (int kv = 0; kv < 2; ++kv) {
            f16x8 t;
#pragma unroll
            for (int j = 0; j < 8; ++j)
              t[j] = oh[(kv * 32 + quad * 8 + j) * 40 + nt * 16 + m];
            bvF[view][nt][kv] = t;
          }
      }
    }
  }
  __syncthreads();   // all fragments in regs; sm free

  // ================= attention + proj, both views =================
#pragma unroll
  for (int view = 0; view < 2; ++view) {
    const float* __restrict__ pcw = view ? pcw2 : pcw1;
    float pcwf[16];
#pragma unroll
    for (int c = 0; c < 16; ++c) pcwf[c] = pcw[h * 16 + c];
    const float pcb_h = (view ? pcb2 : pcb1)[h];
    const float lsv = (view ? ls2 : ls1)[h];
    const float scale_h = __expf(fminf(lsv, 4.6051702f));
    const float pcbs = pcb_h * scale_h;
    for (int i = tid; i < 1800; i += 512) sTbl[i] = sg16[view * 1800 + i];
    __syncthreads();   // sTbl ready; prior-view preB reads done

    f32x4 oacc[4][2];
#pragma unroll
    for (int rt = 0; rt < 4; ++rt) {
      f16x8 aq = aqF[view][rt];
      f32x4 Ss[4], Sd[4];
#pragma unroll
      for (int ct = 0; ct < 4; ++ct) {
        Ss[ct] = MFMA_F16(aq, kfF[view][ct], z4);
        Sd[ct] = MFMA_F16(aq, kfF[1 - view][ct], z4);
      }
#pragma unroll
      for (int ct = 0; ct < 4; ++ct)
#pragma unroll
        for (int r = 0; r < 4; ++r) {
          Sb[(quad * 4 + r) * SB_STRIDE + (ct * 16 + m) * 24 + h]     = (f16)Ss[ct][r];
          Sb[(quad * 4 + r) * SB_STRIDE + (ct * 16 + m) * 24 + 8 + h] = (f16)Sd[ct][r];
        }
      __syncthreads();   // B1: Sb complete (all heads' channels)

      // ---- logits: direct 16-channel mix from Sb; softmax; AV ----
      const int n = rt * 16 + m;
      const int nh_ = n >> 3, nw_ = n & 7;
      const f16* srow = Sb + m * SB_STRIDE;
      float logit[16];
#pragma unroll
      for (int j = 0; j < 16; ++j) {
        int mm = (j < 8) ? (quad * 8 + j) : (32 + quad * 8 + (j - 8));
        f16x8 s0 = *(const f16x8*)(srow + mm * 24);
        f16x8 s1 = *(const f16x8*)(srow + mm * 24 + 8);
        float mix = 0.f;
#pragma unroll
        for (int c = 0; c < 8; ++c)
          mix += pcwf[c] * (float)s0[c] + pcwf[8 + c] * (float)s1[c];
        int idx = (nh_ - (mm >> 3) + 7) * 15 + (nw_ - (mm & 7) + 7);
        logit[j] = mix * scale_h + pcbs + sTbl[idx * 8 + h];
      }
      float mx = -1e30f;
#pragma unroll
      for (int j = 0; j < 16; ++j) mx = fmaxf(mx, logit[j]);
      mx = fmaxf(mx, __shfl_xor(mx, 16, 64));
      mx = fmaxf(mx, __shfl_xor(mx, 32, 64));
      float p[16], sum = 0.f;
#pragma unroll
      for (int j = 0; j < 16; ++j) { p[j] = __expf(logit[j] - mx); sum += p[j]; }
      sum += __shfl_xor(sum, 16, 64);
      sum += __shfl_xor(sum, 32, 64);
      float inv = 1.0f / sum;
      f16x8 av0, av1;
#pragma unroll
      for (int j = 0; j < 8; ++j) { av0[j] = (f16)(p[j] * inv); av1[j] = (f16)(p[8 + j] * inv); }
#pragma unroll
      for (int nt = 0; nt < 2; ++nt) {
        f32x4 z = z4;
        z = MFMA_F16(av0, bvF[view][nt][0], z);
        z = MFMA_F16(av1, bvF[view][nt][1], z);
        oacc[rt][nt] = z;
      }
      __syncthreads();   // B2: Sb reads done before next rt overwrites
    }

    // ---- pre-projection activations -> preB ----
#pragma unroll
    for (int mt = 0; mt < 4; ++mt)
#pragma unroll
      for (int nt = 0; nt < 2; ++nt)
#pragma unroll
        for (int r = 0; r < 4; ++r)
          preB[(mt * 16 + quad * 4 + r) * 264 + h * 32 + nt * 16 + m] = (f16)oacc[mt][nt][r];
    __syncthreads();   // preB ready

    // ---- proj GEMM from preB ----
    const float* __restrict__ Wp = view ? pw2 : pw1;
    const float* __restrict__ pb = view ? pb2 : pb1;
    f32x4 pacc0[4], pacc1[4];
#pragma unroll
    for (int t = 0; t < 4; ++t) { pacc0[t] = z4; pacc1[t] = z4; }
    for (int ks = 0; ks < 8; ++ks) {
      f16x8 pa0 = ld_f16x8(Wp + (size_t)(h * 32 + m) * 256 + ks * 32 + quad * 8);
      f16x8 pa1 = ld_f16x8(Wp + (size_t)(h * 32 + 16 + m) * 256 + ks * 32 + quad * 8);
#pragma unroll
      for (int tt = 0; tt < 4; ++tt) {
        f16x8 bfr = *(const f16x8*)(preB + (tt * 16 + m) * 264 + ks * 32 + quad * 8);
        pacc0[tt] = MFMA_F16(pa0, bfr, pacc0[tt]);
        pacc1[tt] = MFMA_F16(pa1, bfr, pacc1[tt]);
      }
    }
    // ---- FP32 output store (reference output dtype is float32) ----
    float* obase = outp + (size_t)(view * NWIN + win) * (NTOK * DIM);
#pragma unroll
    for (int tt = 0; tt < 4; ++tt) {
      f32x4 p0, p1;
#pragma unroll
      for (int r = 0; r < 4; ++r) {
        p0[r] = pacc0[tt][r] + pb[h * 32 + quad * 4 + r];
        p1[r] = pacc1[tt][r] + pb[h * 32 + 16 + quad * 4 + r];
      }
      const int n = tt * 16 + m;
      *(f32x4*)(obase + n * 256 + h * 32 + quad * 4)      = p0;
      *(f32x4*)(obase + n * 256 + h * 32 + 16 + quad * 4) = p1;
    }
    __syncthreads();   // preB reads done before next view reuses sm
  }
}

extern "C" void kernel_launch(void* const* d_in, const int* in_sizes, int n_in,
                              void* d_out, int out_size, void* d_ws, size_t ws_size,
                              hipStream_t stream) {
  (void)in_sizes; (void)n_in; (void)out_size; (void)ws_size;
  const float* x1   = (const float*)d_in[0];
  const float* x2   = (const float*)d_in[1];
  const float* qkvw1= (const float*)d_in[2];
  const float* qb1  = (const float*)d_in[3];
  const float* vb1  = (const float*)d_in[4];
  const float* pw1  = (const float*)d_in[5];
  const float* pb1  = (const float*)d_in[6];
  const float* ls1  = (const float*)d_in[7];
  const float* cw11 = (const float*)d_in[8];
  const float* cb11 = (const float*)d_in[9];
  const float* cw12 = (const float*)d_in[10];
  const float* pcw1 = (const float*)d_in[11];
  const float* pcb1 = (const float*)d_in[12];
  const float* qkvw2= (const float*)d_in[13];
  const float* qb2  = (const float*)d_in[14];
  const float* vb2  = (const float*)d_in[15];
  const float* pw2  = (const float*)d_in[16];
  const float* pb2  = (const float*)d_in[17];
  const float* ls2  = (const float*)d_in[18];
  const float* cw21 = (const float*)d_in[19];
  const float* cb21 = (const float*)d_in[20];
  const float* cw22 = (const float*)d_in[21];
  const float* pcw2 = (const float*)d_in[22];
  const float* pcb2 = (const float*)d_in[23];

  float* SG16 = (float*)d_ws;    // [2][225][8] f32 = 14.4 KB (only ws use)
  float* out = (float*)d_out;

  prep_cpb<<<450, 256, 0, stream>>>(cw11, cb11, cw12, cw21, cb21, cw22, SG16);
  fused_attn<<<NWIN, 512, 0, stream>>>(x1, x2,
      qkvw1, qb1, vb1, qkvw2, qb2, vb2,
      pcw1, pcb1, ls1, pcw2, pcb2, ls2,
      pw1, pb1, pw2, pb2, SG16, out);
}

// Round 2
// 356.907 us; speedup vs baseline: 1.3459x; 1.0830x over previous
//
#include <hip/hip_runtime.h>

typedef _Float16 f16;
typedef f16  f16x8  __attribute__((ext_vector_type(8)));
typedef f16  f16x4v __attribute__((ext_vector_type(4)));
typedef float f32x4 __attribute__((ext_vector_type(4)));

#define MFMA_F16(a,b,c) __builtin_amdgcn_mfma_f32_16x16x32_f16((a),(b),(c),0,0,0)

#define NWIN 512
// Sb: [16 qrows][64 k][16ch + 8 pad] f16, row stride 1544 f16 (3088 B ≡ 16 mod 128)
#define SB_STRIDE 1544
// full-x staging: [64 tok][256 + 8 pad] f16 (528 B row ≡ 16 mod 128 -> 2-way free)
#define BUFX_ST 264
// per-head QKV output scratch: Q/K swizzled [64][32] (4096 B), V transposed [32][72]
#define BUFO_HEAD 2304
#define VT_ST 72
// sm layout: bufX [0,33792) | bufO [33792,70656)
// attention reuse: Sb [0,49408) | sTbl [49408,63808)  (49408 = multiple of 128)
#define SM_BYTES 70656
#define STBL_OFF 49408

// load 8 consecutive fp32, round to f16x8
__device__ __forceinline__ f16x8 ld_f16x8(const float* __restrict__ p) {
  f32x4 a = *(const f32x4*)p;
  f32x4 b = *(const f32x4*)(p + 4);
  f16x8 r;
  r[0] = (f16)a[0]; r[1] = (f16)a[1]; r[2] = (f16)a[2]; r[3] = (f16)a[3];
  r[4] = (f16)b[0]; r[5] = (f16)b[1]; r[6] = (f16)b[2]; r[7] = (f16)b[3];
  return r;
}

// ---------------- prep: CPB MLP table + weight f32->f16 conversion ----------
// blocks [0,450): cpb (view*225 + entry); blocks [450,706): weight conversion.
__global__ __launch_bounds__(256) void prep_all(
    const float* __restrict__ w1a, const float* __restrict__ b1a,
    const float* __restrict__ w2a,
    const float* __restrict__ w1b, const float* __restrict__ b1b,
    const float* __restrict__ w2b,
    const float* __restrict__ qkvw1, const float* __restrict__ qkvw2,
    const float* __restrict__ pw1, const float* __restrict__ pw2,
    float* __restrict__ sg16,
    f16* __restrict__ wq1f, f16* __restrict__ wq2f,
    f16* __restrict__ pw1f, f16* __restrict__ pw2f) {
  const int b = blockIdx.x;
  if (b >= 450) {
    // weight conversion: 2048 f32 per block, vectorized.
    const int cb = b - 450;
    const float* src; f16* dst; int base;
    if (cb < 96)       { src = qkvw1; dst = wq1f; base = cb * 2048; }
    else if (cb < 192) { src = qkvw2; dst = wq2f; base = (cb - 96) * 2048; }
    else if (cb < 224) { src = pw1;   dst = pw1f; base = (cb - 192) * 2048; }
    else               { src = pw2;   dst = pw2f; base = (cb - 224) * 2048; }
    const int o = base + threadIdx.x * 8;
    *(f16x8*)(dst + o) = ld_f16x8(src + o);
    return;
  }
  const int view = b / 225;
  const int e    = b % 225;
  const float* __restrict__ w1 = view ? w1b : w1a;
  const float* __restrict__ b1 = view ? b1b : b1a;
  const float* __restrict__ w2 = view ? w2b : w2a;
  const int t = threadIdx.x;
  const int i = e / 15, j = e % 15;
  const float vi = 8.0f * (float)(i - 7) * (1.0f / 7.0f);
  const float vj = 8.0f * (float)(j - 7) * (1.0f / 7.0f);
  const float in0 = copysignf(log2f(fabsf(vi) + 1.0f) * (1.0f / 3.0f), vi);
  const float in1 = copysignf(log2f(fabsf(vj) + 1.0f) * (1.0f / 3.0f), vj);
  float acc[8] = {0.f,0.f,0.f,0.f,0.f,0.f,0.f,0.f};
#pragma unroll
  for (int uu = 0; uu < 2; ++uu) {
    const int u = t + uu * 256;
    float hv = fmaxf(w1[2*u] * in0 + w1[2*u+1] * in1 + b1[u], 0.0f);
#pragma unroll
    for (int hh = 0; hh < 8; ++hh) acc[hh] += w2[hh*512 + u] * hv;
  }
#pragma unroll
  for (int off = 32; off >= 1; off >>= 1)
#pragma unroll
    for (int hh = 0; hh < 8; ++hh) acc[hh] += __shfl_xor(acc[hh], off, 64);
  __shared__ float red[4][8];
  if ((t & 63) == 0) {
#pragma unroll
    for (int hh = 0; hh < 8; ++hh) red[t >> 6][hh] = acc[hh];
  }
  __syncthreads();
  if (t < 8) {
    float s = red[0][t] + red[1][t] + red[2][t] + red[3][t];
    sg16[(view * 225 + e) * 8 + t] = 16.0f / (1.0f + __expf(-s));
  }
}

// ---------------- fused: per-window (both views) QKV + attention + proj ------
__global__ __launch_bounds__(512, 4) void fused_attn(
    const float* __restrict__ x1, const float* __restrict__ x2,
    const f16* __restrict__ qkvw1, const float* __restrict__ qb1, const float* __restrict__ vb1,
    const f16* __restrict__ qkvw2, const float* __restrict__ qb2, const float* __restrict__ vb2,
    const float* __restrict__ pcw1, const float* __restrict__ pcb1, const float* __restrict__ ls1,
    const float* __restrict__ pcw2, const float* __restrict__ pcb2, const float* __restrict__ ls2,
    const f16* __restrict__ pw1, const float* __restrict__ pb1,
    const f16* __restrict__ pw2, const float* __restrict__ pb2,
    const float* __restrict__ sg16,
    float* __restrict__ outp) {
  const int win = blockIdx.x;
  const int tid = threadIdx.x;
  const int lane = tid & 63, h = tid >> 6;
  const int quad = lane >> 4, m = lane & 15;

  __shared__ __align__(16) char sm[SM_BYTES];
  f16* bufX  = (f16*)sm;
  f16* bufO  = (f16*)(sm + 33792);
  f16* Sb    = (f16*)sm;
  f16* preB  = (f16*)sm;
  float* sTbl = (float*)(sm + STBL_OFF);

  const f32x4 z4 = {0.f, 0.f, 0.f, 0.f};
  f16x8 aqF[2][4], kfF[2][4], bvF[2][2][2];
  f16* oh = bufO + h * BUFO_HEAD;

  // ================= QKV GEMMs, both views =================
  for (int view = 0; view < 2; ++view) {
    const float* __restrict__ xv = (view ? x2 : x1) + (size_t)win * (64 * 256);
    const f16* __restrict__ W    = view ? qkvw2 : qkvw1;
    const float* __restrict__ qb = view ? qb2 : qb1;
    const float* __restrict__ vb = view ? vb2 : vb1;

    __syncthreads();   // bufX/bufO safe to overwrite (prev view's reads done)
    for (int i = tid; i < 2048; i += 512) {           // 64 rows x 32 chunks of 8
      const int row = i >> 5, c8 = i & 31;
      *(f16x8*)(bufX + row * BUFX_ST + c8 * 8) = ld_f16x8(xv + row * 256 + c8 * 8);
    }
    __syncthreads();   // bufX ready (stable for all 3 secs — no more restaging)

    for (int sec = 0; sec < 3; ++sec) {
      f32x4 acc0[4], acc1[4];
#pragma unroll
      for (int t = 0; t < 4; ++t) { acc0[t] = z4; acc1[t] = z4; }
      const f16* wb = W + (size_t)(sec * 256 + h * 32) * 256 + quad * 8;
#pragma unroll 2
      for (int k8 = 0; k8 < 8; ++k8) {
        f16x8 a0 = *(const f16x8*)(wb + (size_t)m * 256 + k8 * 32);
        f16x8 a1 = *(const f16x8*)(wb + (size_t)(16 + m) * 256 + k8 * 32);
#pragma unroll
        for (int tt = 0; tt < 4; ++tt) {
          f16x8 bfr = *(const f16x8*)(bufX + (tt * 16 + m) * BUFX_ST + k8 * 32 + quad * 8);
          acc0[tt] = MFMA_F16(a0, bfr, acc0[tt]);
          acc1[tt] = MFMA_F16(a1, bfr, acc1[tt]);
        }
      }
      // epilogue: bias, (l2norm q/k), write to own head's bufO region.
      float bs0[4], bs1[4];
#pragma unroll
      for (int r = 0; r < 4; ++r) {
        int c0 = h * 32 + quad * 4 + r;
        bs0[r] = (sec == 0) ? qb[c0] : (sec == 2 ? vb[c0] : 0.f);
        bs1[r] = (sec == 0) ? qb[c0 + 16] : (sec == 2 ? vb[c0 + 16] : 0.f);
      }
#pragma unroll
      for (int tt = 0; tt < 4; ++tt) {
        float v0[4], v1[4];
#pragma unroll
        for (int r = 0; r < 4; ++r) { v0[r] = acc0[tt][r] + bs0[r]; v1[r] = acc1[tt][r] + bs1[r]; }
        if (sec < 2) {
          float ss = 0.f;
#pragma unroll
          for (int r = 0; r < 4; ++r) ss += v0[r] * v0[r] + v1[r] * v1[r];
          ss += __shfl_xor(ss, 16, 64);
          ss += __shfl_xor(ss, 32, 64);
          float s = 1.0f / fmaxf(sqrtf(ss), 1e-12f);
#pragma unroll
          for (int r = 0; r < 4; ++r) { v0[r] *= s; v1[r] *= s; }
        }
        const int n = tt * 16 + m;
        if (sec < 2) {
          // Q/K: swizzled [tok][32ch] layout; XOR of byte bits 4-6 with (n&7)
          // is a bijective (triangular) map — keeps writes ~conflict-free.
          f16x4v p0, p1;
#pragma unroll
          for (int r = 0; r < 4; ++r) { p0[r] = (f16)v0[r]; p1[r] = (f16)v1[r]; }
          char* ob = (char*)oh;
          const int sw = (n & 7) << 4;
          *(f16x4v*)(ob + ((n * 64 + quad * 8) ^ sw))      = p0;
          *(f16x4v*)(ob + ((n * 64 + 32 + quad * 8) ^ sw)) = p1;
        } else {
          // V: store transposed Vt[ch][tok] so fragment reads are vector loads
#pragma unroll
          for (int r = 0; r < 4; ++r) {
            oh[(quad * 4 + r) * VT_ST + n]      = (f16)v0[r];
            oh[(quad * 4 + 16 + r) * VT_ST + n] = (f16)v1[r];
          }
        }
      }
      // fragment extraction — own-head region only, no barrier needed
      if (sec == 0) {
#pragma unroll
        for (int rt = 0; rt < 4; ++rt) {
          const int n = rt * 16 + m;
          aqF[view][rt] = *(const f16x8*)((char*)oh + ((n * 64 + quad * 16) ^ ((n & 7) << 4)));
        }
      } else if (sec == 1) {
#pragma unroll
        for (int ct = 0; ct < 4; ++ct) {
          const int n = ct * 16 + m;
          kfF[view][ct] = *(const f16x8*)((char*)oh + ((n * 64 + quad * 16) ^ ((n & 7) << 4)));
        }
      } else {
#pragma unroll
        for (int nt = 0; nt < 2; ++nt)
#pragma unroll
          for (int kv = 0; kv < 2; ++kv)
            bvF[view][nt][kv] = *(const f16x8*)(oh + (nt * 16 + m) * VT_ST + kv * 32 + quad * 8);
      }
    }
  }
  __syncthreads();   // all fragments in regs; sm free for Sb/sTbl

  // load bias table once for BOTH views (sTbl region disjoint from Sb/preB)
  for (int i = tid; i < 3600; i += 512) sTbl[i] = sg16[i];

  // ================= attention + proj, both views =================
#pragma unroll
  for (int view = 0; view < 2; ++view) {
    const float* __restrict__ pcw = view ? pcw2 : pcw1;
    float pcwf[16];
#pragma unroll
    for (int c = 0; c < 16; ++c) pcwf[c] = pcw[h * 16 + c];
    const float pcb_h = (view ? pcb2 : pcb1)[h];
    const float lsv = (view ? ls2 : ls1)[h];
    const float scale_h = __expf(fminf(lsv, 4.6051702f));
    const float pcbs = pcb_h * scale_h;
    const float* tblv = sTbl + view * 1800;

    f32x4 oacc[4][2];
#pragma unroll
    for (int rt = 0; rt < 4; ++rt) {
      f16x8 aq = aqF[view][rt];
      f32x4 Ss[4], Sd[4];
#pragma unroll
      for (int ct = 0; ct < 4; ++ct) {
        Ss[ct] = MFMA_F16(aq, kfF[view][ct], z4);
        Sd[ct] = MFMA_F16(aq, kfF[1 - view][ct], z4);
      }
#pragma unroll
      for (int ct = 0; ct < 4; ++ct)
#pragma unroll
        for (int r = 0; r < 4; ++r) {
          Sb[(quad * 4 + r) * SB_STRIDE + (ct * 16 + m) * 24 + h]     = (f16)Ss[ct][r];
          Sb[(quad * 4 + r) * SB_STRIDE + (ct * 16 + m) * 24 + 8 + h] = (f16)Sd[ct][r];
        }
      __syncthreads();   // B1: Sb complete (all heads' channels)

      // ---- logits: direct 16-channel mix from Sb; softmax; AV ----
      const int n = rt * 16 + m;
      const int nh_ = n >> 3, nw_ = n & 7;
      const f16* srow = Sb + m * SB_STRIDE;
      float logit[16];
#pragma unroll
      for (int j = 0; j < 16; ++j) {
        int mm = (j < 8) ? (quad * 8 + j) : (32 + quad * 8 + (j - 8));
        f16x8 s0 = *(const f16x8*)(srow + mm * 24);
        f16x8 s1 = *(const f16x8*)(srow + mm * 24 + 8);
        float mix = 0.f;
#pragma unroll
        for (int c = 0; c < 8; ++c)
          mix += pcwf[c] * (float)s0[c] + pcwf[8 + c] * (float)s1[c];
        int idx = (nh_ - (mm >> 3) + 7) * 15 + (nw_ - (mm & 7) + 7);
        logit[j] = mix * scale_h + pcbs + tblv[idx * 8 + h];
      }
      float mx = -1e30f;
#pragma unroll
      for (int j = 0; j < 16; ++j) mx = fmaxf(mx, logit[j]);
      mx = fmaxf(mx, __shfl_xor(mx, 16, 64));
      mx = fmaxf(mx, __shfl_xor(mx, 32, 64));
      float p[16], sum = 0.f;
#pragma unroll
      for (int j = 0; j < 16; ++j) { p[j] = __expf(logit[j] - mx); sum += p[j]; }
      sum += __shfl_xor(sum, 16, 64);
      sum += __shfl_xor(sum, 32, 64);
      float inv = 1.0f / sum;
      f16x8 av0, av1;
#pragma unroll
      for (int j = 0; j < 8; ++j) { av0[j] = (f16)(p[j] * inv); av1[j] = (f16)(p[8 + j] * inv); }
#pragma unroll
      for (int nt = 0; nt < 2; ++nt) {
        f32x4 z = z4;
        z = MFMA_F16(av0, bvF[view][nt][0], z);
        z = MFMA_F16(av1, bvF[view][nt][1], z);
        oacc[rt][nt] = z;
      }
      __syncthreads();   // B2: Sb reads done before next rt overwrites
    }

    // ---- pre-projection activations -> preB ----
#pragma unroll
    for (int mt = 0; mt < 4; ++mt)
#pragma unroll
      for (int nt = 0; nt < 2; ++nt)
#pragma unroll
        for (int r = 0; r < 4; ++r)
          preB[(mt * 16 + quad * 4 + r) * 264 + h * 32 + nt * 16 + m] = (f16)oacc[mt][nt][r];
    __syncthreads();   // preB ready

    // ---- proj GEMM from preB (f16 weights) ----
    const f16* __restrict__ Wp = view ? pw2 : pw1;
    const float* __restrict__ pb = view ? pb2 : pb1;
    f32x4 pacc0[4], pacc1[4];
#pragma unroll
    for (int t = 0; t < 4; ++t) { pacc0[t] = z4; pacc1[t] = z4; }
#pragma unroll 2
    for (int ks = 0; ks < 8; ++ks) {
      f16x8 pa0 = *(const f16x8*)(Wp + (size_t)(h * 32 + m) * 256 + ks * 32 + quad * 8);
      f16x8 pa1 = *(const f16x8*)(Wp + (size_t)(h * 32 + 16 + m) * 256 + ks * 32 + quad * 8);
#pragma unroll
      for (int tt = 0; tt < 4; ++tt) {
        f16x8 bfr = *(const f16x8*)(preB + (tt * 16 + m) * 264 + ks * 32 + quad * 8);
        pacc0[tt] = MFMA_F16(pa0, bfr, pacc0[tt]);
        pacc1[tt] = MFMA_F16(pa1, bfr, pacc1[tt]);
      }
    }
    // ---- FP32 output store ----
    float* obase = outp + (size_t)(view * NWIN + win) * (64 * 256);
#pragma unroll
    for (int tt = 0; tt < 4; ++tt) {
      f32x4 p0, p1;
#pragma unroll
      for (int r = 0; r < 4; ++r) {
        p0[r] = pacc0[tt][r] + pb[h * 32 + quad * 4 + r];
        p1[r] = pacc1[tt][r] + pb[h * 32 + 16 + quad * 4 + r];
      }
      const int n = tt * 16 + m;
      *(f32x4*)(obase + n * 256 + h * 32 + quad * 4)      = p0;
      *(f32x4*)(obase + n * 256 + h * 32 + 16 + quad * 4) = p1;
    }
    __syncthreads();   // preB/Sb reads done before next view reuses sm
  }
}

extern "C" void kernel_launch(void* const* d_in, const int* in_sizes, int n_in,
                              void* d_out, int out_size, void* d_ws, size_t ws_size,
                              hipStream_t stream) {
  (void)in_sizes; (void)n_in; (void)out_size; (void)ws_size;
  const float* x1   = (const float*)d_in[0];
  const float* x2   = (const float*)d_in[1];
  const float* qkvw1= (const float*)d_in[2];
  const float* qb1  = (const float*)d_in[3];
  const float* vb1  = (const float*)d_in[4];
  const float* pw1  = (const float*)d_in[5];
  const float* pb1  = (const float*)d_in[6];
  const float* ls1  = (const float*)d_in[7];
  const float* cw11 = (const float*)d_in[8];
  const float* cb11 = (const float*)d_in[9];
  const float* cw12 = (const float*)d_in[10];
  const float* pcw1 = (const float*)d_in[11];
  const float* pcb1 = (const float*)d_in[12];
  const float* qkvw2= (const float*)d_in[13];
  const float* qb2  = (const float*)d_in[14];
  const float* vb2  = (const float*)d_in[15];
  const float* pw2  = (const float*)d_in[16];
  const float* pb2  = (const float*)d_in[17];
  const float* ls2  = (const float*)d_in[18];
  const float* cw21 = (const float*)d_in[19];
  const float* cb21 = (const float*)d_in[20];
  const float* cw22 = (const float*)d_in[21];
  const float* pcw2 = (const float*)d_in[22];
  const float* pcb2 = (const float*)d_in[23];

  // workspace layout: sg16 [2][225][8] f32 (14400 B) | qkvw1 f16 (393216 B) |
  // qkvw2 f16 | pw1 f16 (131072 B) | pw2 f16  -> total ~1.04 MB
  float* SG16 = (float*)d_ws;
  f16* wq1f = (f16*)((char*)d_ws + 14400);
  f16* wq2f = wq1f + 196608;
  f16* pw1f = wq2f + 196608;
  f16* pw2f = pw1f + 65536;
  float* out = (float*)d_out;

  prep_all<<<706, 256, 0, stream>>>(cw11, cb11, cw12, cw21, cb21, cw22,
                                    qkvw1, qkvw2, pw1, pw2,
                                    SG16, wq1f, wq2f, pw1f, pw2f);
  fused_attn<<<NWIN, 512, 0, stream>>>(x1, x2,
      wq1f, qb1, vb1, wq2f, qb2, vb2,
      pcw1, pcb1, ls1, pcw2, pcb2, ls2,
      pw1f, pb1, pw2f, pb2, SG16, out);
}

// Round 3
// 301.172 us; speedup vs baseline: 1.5950x; 1.1851x over previous
//
#include <hip/hip_runtime.h>

typedef _Float16 f16;
typedef f16  f16x8  __attribute__((ext_vector_type(8)));
typedef f16  f16x4v __attribute__((ext_vector_type(4)));
typedef float f32x4 __attribute__((ext_vector_type(4)));

#define MFMA_F16(a,b,c) __builtin_amdgcn_mfma_f32_16x16x32_f16((a),(b),(c),0,0,0)

#define NWIN 512
// Sb: [16 qrows][64 k][16ch + 8 pad] f16, row stride 1544 f16 (3088 B ≡ 16 mod 128)
#define SB_STRIDE 1544
// full-x staging: [64 tok][256 + 8 pad] f16 (528 B row ≡ 16 mod 128 -> 2-way free)
#define BUFX_ST 264
// per-head QKV output scratch: Q/K swizzled [64][32] (4096 B), V transposed [32][72]
#define BUFO_HEAD 2304
#define VT_ST 72
// sm layout: bufX [0,33792) | bufO [33792,70656)
// attention reuse: Sb [0,49408) | sTbl [49408,63808)  (49408 = multiple of 128)
#define SM_BYTES 70656
#define STBL_OFF 49408

// load 8 consecutive fp32, round to f16x8
__device__ __forceinline__ f16x8 ld_f16x8(const float* __restrict__ p) {
  f32x4 a = *(const f32x4*)p;
  f32x4 b = *(const f32x4*)(p + 4);
  f16x8 r;
  r[0] = (f16)a[0]; r[1] = (f16)a[1]; r[2] = (f16)a[2]; r[3] = (f16)a[3];
  r[4] = (f16)b[0]; r[5] = (f16)b[1]; r[6] = (f16)b[2]; r[7] = (f16)b[3];
  return r;
}

// ---------------- prep: CPB MLP table + weight f32->f16 conversion ----------
// blocks [0,450): cpb (view*225 + entry); blocks [450,706): weight conversion.
__global__ __launch_bounds__(256) void prep_all(
    const float* __restrict__ w1a, const float* __restrict__ b1a,
    const float* __restrict__ w2a,
    const float* __restrict__ w1b, const float* __restrict__ b1b,
    const float* __restrict__ w2b,
    const float* __restrict__ qkvw1, const float* __restrict__ qkvw2,
    const float* __restrict__ pw1, const float* __restrict__ pw2,
    float* __restrict__ sg16,
    f16* __restrict__ wq1f, f16* __restrict__ wq2f,
    f16* __restrict__ pw1f, f16* __restrict__ pw2f) {
  const int b = blockIdx.x;
  if (b >= 450) {
    // weight conversion: 2048 f32 per block, vectorized.
    const int cb = b - 450;
    const float* src; f16* dst; int base;
    if (cb < 96)       { src = qkvw1; dst = wq1f; base = cb * 2048; }
    else if (cb < 192) { src = qkvw2; dst = wq2f; base = (cb - 96) * 2048; }
    else if (cb < 224) { src = pw1;   dst = pw1f; base = (cb - 192) * 2048; }
    else               { src = pw2;   dst = pw2f; base = (cb - 224) * 2048; }
    const int o = base + threadIdx.x * 8;
    *(f16x8*)(dst + o) = ld_f16x8(src + o);
    return;
  }
  const int view = b / 225;
  const int e    = b % 225;
  const float* __restrict__ w1 = view ? w1b : w1a;
  const float* __restrict__ b1 = view ? b1b : b1a;
  const float* __restrict__ w2 = view ? w2b : w2a;
  const int t = threadIdx.x;
  const int i = e / 15, j = e % 15;
  const float vi = 8.0f * (float)(i - 7) * (1.0f / 7.0f);
  const float vj = 8.0f * (float)(j - 7) * (1.0f / 7.0f);
  const float in0 = copysignf(log2f(fabsf(vi) + 1.0f) * (1.0f / 3.0f), vi);
  const float in1 = copysignf(log2f(fabsf(vj) + 1.0f) * (1.0f / 3.0f), vj);
  float acc[8] = {0.f,0.f,0.f,0.f,0.f,0.f,0.f,0.f};
#pragma unroll
  for (int uu = 0; uu < 2; ++uu) {
    const int u = t + uu * 256;
    float hv = fmaxf(w1[2*u] * in0 + w1[2*u+1] * in1 + b1[u], 0.0f);
#pragma unroll
    for (int hh = 0; hh < 8; ++hh) acc[hh] += w2[hh*512 + u] * hv;
  }
#pragma unroll
  for (int off = 32; off >= 1; off >>= 1)
#pragma unroll
    for (int hh = 0; hh < 8; ++hh) acc[hh] += __shfl_xor(acc[hh], off, 64);
  __shared__ float red[4][8];
  if ((t & 63) == 0) {
#pragma unroll
    for (int hh = 0; hh < 8; ++hh) red[t >> 6][hh] = acc[hh];
  }
  __syncthreads();
  if (t < 8) {
    float s = red[0][t] + red[1][t] + red[2][t] + red[3][t];
    sg16[(view * 225 + e) * 8 + t] = 16.0f / (1.0f + __expf(-s));
  }
}

// ---------------- fused: per-window (both views) QKV + attention + proj ------
// launch_bounds (512, 2): LDS (70656 B) caps us at 2 blocks/CU anyway; asking
// for 4 (R2) forced VGPR=64 and ~350 MB of scratch spill traffic. 2 -> 128 VGPR.
__global__ __launch_bounds__(512, 2) void fused_attn(
    const float* __restrict__ x1, const float* __restrict__ x2,
    const f16* __restrict__ qkvw1, const float* __restrict__ qb1, const float* __restrict__ vb1,
    const f16* __restrict__ qkvw2, const float* __restrict__ qb2, const float* __restrict__ vb2,
    const float* __restrict__ pcw1, const float* __restrict__ pcb1, const float* __restrict__ ls1,
    const float* __restrict__ pcw2, const float* __restrict__ pcb2, const float* __restrict__ ls2,
    const f16* __restrict__ pw1, const float* __restrict__ pb1,
    const f16* __restrict__ pw2, const float* __restrict__ pb2,
    const float* __restrict__ sg16,
    float* __restrict__ outp) {
  const int win = blockIdx.x;
  const int tid = threadIdx.x;
  const int lane = tid & 63, h = tid >> 6;
  const int quad = lane >> 4, m = lane & 15;

  __shared__ __align__(16) char sm[SM_BYTES];
  f16* bufX  = (f16*)sm;
  f16* bufO  = (f16*)(sm + 33792);
  f16* Sb    = (f16*)sm;
  f16* preB  = (f16*)sm;
  float* sTbl = (float*)(sm + STBL_OFF);

  const f32x4 z4 = {0.f, 0.f, 0.f, 0.f};
  f16x8 aqF[2][4], kfF[2][4], bvF[2][2][2];
  f16* oh = bufO + h * BUFO_HEAD;

  // ================= QKV GEMMs, both views =================
  for (int view = 0; view < 2; ++view) {
    const float* __restrict__ xv = (view ? x2 : x1) + (size_t)win * (64 * 256);
    const f16* __restrict__ W    = view ? qkvw2 : qkvw1;
    const float* __restrict__ qb = view ? qb2 : qb1;
    const float* __restrict__ vb = view ? vb2 : vb1;

    __syncthreads();   // bufX/bufO safe to overwrite (prev view's reads done)
    for (int i = tid; i < 2048; i += 512) {           // 64 rows x 32 chunks of 8
      const int row = i >> 5, c8 = i & 31;
      *(f16x8*)(bufX + row * BUFX_ST + c8 * 8) = ld_f16x8(xv + row * 256 + c8 * 8);
    }
    __syncthreads();   // bufX ready (stable for all 3 secs — no more restaging)

    for (int sec = 0; sec < 3; ++sec) {
      f32x4 acc0[4], acc1[4];
#pragma unroll
      for (int t = 0; t < 4; ++t) { acc0[t] = z4; acc1[t] = z4; }
      const f16* wb = W + (size_t)(sec * 256 + h * 32) * 256 + quad * 8;
#pragma unroll 2
      for (int k8 = 0; k8 < 8; ++k8) {
        f16x8 a0 = *(const f16x8*)(wb + (size_t)m * 256 + k8 * 32);
        f16x8 a1 = *(const f16x8*)(wb + (size_t)(16 + m) * 256 + k8 * 32);
#pragma unroll
        for (int tt = 0; tt < 4; ++tt) {
          f16x8 bfr = *(const f16x8*)(bufX + (tt * 16 + m) * BUFX_ST + k8 * 32 + quad * 8);
          acc0[tt] = MFMA_F16(a0, bfr, acc0[tt]);
          acc1[tt] = MFMA_F16(a1, bfr, acc1[tt]);
        }
      }
      // epilogue: bias, (l2norm q/k), write to own head's bufO region.
      float bs0[4], bs1[4];
#pragma unroll
      for (int r = 0; r < 4; ++r) {
        int c0 = h * 32 + quad * 4 + r;
        bs0[r] = (sec == 0) ? qb[c0] : (sec == 2 ? vb[c0] : 0.f);
        bs1[r] = (sec == 0) ? qb[c0 + 16] : (sec == 2 ? vb[c0 + 16] : 0.f);
      }
#pragma unroll
      for (int tt = 0; tt < 4; ++tt) {
        float v0[4], v1[4];
#pragma unroll
        for (int r = 0; r < 4; ++r) { v0[r] = acc0[tt][r] + bs0[r]; v1[r] = acc1[tt][r] + bs1[r]; }
        if (sec < 2) {
          float ss = 0.f;
#pragma unroll
          for (int r = 0; r < 4; ++r) ss += v0[r] * v0[r] + v1[r] * v1[r];
          ss += __shfl_xor(ss, 16, 64);
          ss += __shfl_xor(ss, 32, 64);
          float s = 1.0f / fmaxf(sqrtf(ss), 1e-12f);
#pragma unroll
          for (int r = 0; r < 4; ++r) { v0[r] *= s; v1[r] *= s; }
        }
        const int n = tt * 16 + m;
        if (sec < 2) {
          // Q/K: swizzled [tok][32ch] layout; XOR of byte bits 4-6 with (n&7)
          // is a bijective (triangular) map — keeps writes ~conflict-free.
          f16x4v p0, p1;
#pragma unroll
          for (int r = 0; r < 4; ++r) { p0[r] = (f16)v0[r]; p1[r] = (f16)v1[r]; }
          char* ob = (char*)oh;
          const int sw = (n & 7) << 4;
          *(f16x4v*)(ob + ((n * 64 + quad * 8) ^ sw))      = p0;
          *(f16x4v*)(ob + ((n * 64 + 32 + quad * 8) ^ sw)) = p1;
        } else {
          // V: store transposed Vt[ch][tok] so fragment reads are vector loads
#pragma unroll
          for (int r = 0; r < 4; ++r) {
            oh[(quad * 4 + r) * VT_ST + n]      = (f16)v0[r];
            oh[(quad * 4 + 16 + r) * VT_ST + n] = (f16)v1[r];
          }
        }
      }
      // fragment extraction — own-head region only, no barrier needed
      if (sec == 0) {
#pragma unroll
        for (int rt = 0; rt < 4; ++rt) {
          const int n = rt * 16 + m;
          aqF[view][rt] = *(const f16x8*)((char*)oh + ((n * 64 + quad * 16) ^ ((n & 7) << 4)));
        }
      } else if (sec == 1) {
#pragma unroll
        for (int ct = 0; ct < 4; ++ct) {
          const int n = ct * 16 + m;
          kfF[view][ct] = *(const f16x8*)((char*)oh + ((n * 64 + quad * 16) ^ ((n & 7) << 4)));
        }
      } else {
#pragma unroll
        for (int nt = 0; nt < 2; ++nt)
#pragma unroll
          for (int kv = 0; kv < 2; ++kv)
            bvF[view][nt][kv] = *(const f16x8*)(oh + (nt * 16 + m) * VT_ST + kv * 32 + quad * 8);
      }
    }
  }
  __syncthreads();   // all fragments in regs; sm free for Sb/sTbl

  // load bias table once for BOTH views (sTbl region disjoint from Sb/preB)
  for (int i = tid; i < 3600; i += 512) sTbl[i] = sg16[i];

  // ================= attention + proj, both views =================
#pragma unroll
  for (int view = 0; view < 2; ++view) {
    const float* __restrict__ pcw = view ? pcw2 : pcw1;
    float pcwf[16];
#pragma unroll
    for (int c = 0; c < 16; ++c) pcwf[c] = pcw[h * 16 + c];
    const float pcb_h = (view ? pcb2 : pcb1)[h];
    const float lsv = (view ? ls2 : ls1)[h];
    const float scale_h = __expf(fminf(lsv, 4.6051702f));
    const float pcbs = pcb_h * scale_h;
    const float* tblv = sTbl + view * 1800;

    f32x4 oacc[4][2];
#pragma unroll
    for (int rt = 0; rt < 4; ++rt) {
      f16x8 aq = aqF[view][rt];
      // compute each score tile and write it out immediately — keeps only one
      // f32x4 pair live instead of Ss[4]+Sd[4] (peak VGPR pressure trim).
#pragma unroll
      for (int ct = 0; ct < 4; ++ct) {
        f32x4 Ss = MFMA_F16(aq, kfF[view][ct], z4);
#pragma unroll
        for (int r = 0; r < 4; ++r)
          Sb[(quad * 4 + r) * SB_STRIDE + (ct * 16 + m) * 24 + h] = (f16)Ss[r];
        f32x4 Sd = MFMA_F16(aq, kfF[1 - view][ct], z4);
#pragma unroll
        for (int r = 0; r < 4; ++r)
          Sb[(quad * 4 + r) * SB_STRIDE + (ct * 16 + m) * 24 + 8 + h] = (f16)Sd[r];
      }
      __syncthreads();   // B1: Sb complete (all heads' channels)

      // ---- logits: direct 16-channel mix from Sb; softmax; AV ----
      const int n = rt * 16 + m;
      const int nh_ = n >> 3, nw_ = n & 7;
      const f16* srow = Sb + m * SB_STRIDE;
      float logit[16];
#pragma unroll
      for (int j = 0; j < 16; ++j) {
        int mm = (j < 8) ? (quad * 8 + j) : (32 + quad * 8 + (j - 8));
        f16x8 s0 = *(const f16x8*)(srow + mm * 24);
        f16x8 s1 = *(const f16x8*)(srow + mm * 24 + 8);
        float mix = 0.f;
#pragma unroll
        for (int c = 0; c < 8; ++c)
          mix += pcwf[c] * (float)s0[c] + pcwf[8 + c] * (float)s1[c];
        int idx = (nh_ - (mm >> 3) + 7) * 15 + (nw_ - (mm & 7) + 7);
        logit[j] = mix * scale_h + pcbs + tblv[idx * 8 + h];
      }
      float mx = -1e30f;
#pragma unroll
      for (int j = 0; j < 16; ++j) mx = fmaxf(mx, logit[j]);
      mx = fmaxf(mx, __shfl_xor(mx, 16, 64));
      mx = fmaxf(mx, __shfl_xor(mx, 32, 64));
      float p[16], sum = 0.f;
#pragma unroll
      for (int j = 0; j < 16; ++j) { p[j] = __expf(logit[j] - mx); sum += p[j]; }
      sum += __shfl_xor(sum, 16, 64);
      sum += __shfl_xor(sum, 32, 64);
      float inv = 1.0f / sum;
      f16x8 av0, av1;
#pragma unroll
      for (int j = 0; j < 8; ++j) { av0[j] = (f16)(p[j] * inv); av1[j] = (f16)(p[8 + j] * inv); }
#pragma unroll
      for (int nt = 0; nt < 2; ++nt) {
        f32x4 z = z4;
        z = MFMA_F16(av0, bvF[view][nt][0], z);
        z = MFMA_F16(av1, bvF[view][nt][1], z);
        oacc[rt][nt] = z;
      }
      __syncthreads();   // B2: Sb reads done before next rt overwrites
    }

    // ---- pre-projection activations -> preB ----
#pragma unroll
    for (int mt = 0; mt < 4; ++mt)
#pragma unroll
      for (int nt = 0; nt < 2; ++nt)
#pragma unroll
        for (int r = 0; r < 4; ++r)
          preB[(mt * 16 + quad * 4 + r) * 264 + h * 32 + nt * 16 + m] = (f16)oacc[mt][nt][r];
    __syncthreads();   // preB ready

    // ---- proj GEMM from preB (f16 weights) ----
    const f16* __restrict__ Wp = view ? pw2 : pw1;
    const float* __restrict__ pb = view ? pb2 : pb1;
    f32x4 pacc0[4], pacc1[4];
#pragma unroll
    for (int t = 0; t < 4; ++t) { pacc0[t] = z4; pacc1[t] = z4; }
#pragma unroll 2
    for (int ks = 0; ks < 8; ++ks) {
      f16x8 pa0 = *(const f16x8*)(Wp + (size_t)(h * 32 + m) * 256 + ks * 32 + quad * 8);
      f16x8 pa1 = *(const f16x8*)(Wp + (size_t)(h * 32 + 16 + m) * 256 + ks * 32 + quad * 8);
#pragma unroll
      for (int tt = 0; tt < 4; ++tt) {
        f16x8 bfr = *(const f16x8*)(preB + (tt * 16 + m) * 264 + ks * 32 + quad * 8);
        pacc0[tt] = MFMA_F16(pa0, bfr, pacc0[tt]);
        pacc1[tt] = MFMA_F16(pa1, bfr, pacc1[tt]);
      }
    }
    // ---- FP32 output store ----
    float* obase = outp + (size_t)(view * NWIN + win) * (64 * 256);
#pragma unroll
    for (int tt = 0; tt < 4; ++tt) {
      f32x4 p0, p1;
#pragma unroll
      for (int r = 0; r < 4; ++r) {
        p0[r] = pacc0[tt][r] + pb[h * 32 + quad * 4 + r];
        p1[r] = pacc1[tt][r] + pb[h * 32 + 16 + quad * 4 + r];
      }
      const int n = tt * 16 + m;
      *(f32x4*)(obase + n * 256 + h * 32 + quad * 4)      = p0;
      *(f32x4*)(obase + n * 256 + h * 32 + 16 + quad * 4) = p1;
    }
    __syncthreads();   // preB/Sb reads done before next view reuses sm
  }
}

extern "C" void kernel_launch(void* const* d_in, const int* in_sizes, int n_in,
                              void* d_out, int out_size, void* d_ws, size_t ws_size,
                              hipStream_t stream) {
  (void)in_sizes; (void)n_in; (void)out_size; (void)ws_size;
  const float* x1   = (const float*)d_in[0];
  const float* x2   = (const float*)d_in[1];
  const float* qkvw1= (const float*)d_in[2];
  const float* qb1  = (const float*)d_in[3];
  const float* vb1  = (const float*)d_in[4];
  const float* pw1  = (const float*)d_in[5];
  const float* pb1  = (const float*)d_in[6];
  const float* ls1  = (const float*)d_in[7];
  const float* cw11 = (const float*)d_in[8];
  const float* cb11 = (const float*)d_in[9];
  const float* cw12 = (const float*)d_in[10];
  const float* pcw1 = (const float*)d_in[11];
  const float* pcb1 = (const float*)d_in[12];
  const float* qkvw2= (const float*)d_in[13];
  const float* qb2  = (const float*)d_in[14];
  const float* vb2  = (const float*)d_in[15];
  const float* pw2  = (const float*)d_in[16];
  const float* pb2  = (const float*)d_in[17];
  const float* ls2  = (const float*)d_in[18];
  const float* cw21 = (const float*)d_in[19];
  const float* cb21 = (const float*)d_in[20];
  const float* cw22 = (const float*)d_in[21];
  const float* pcw2 = (const float*)d_in[22];
  const float* pcb2 = (const float*)d_in[23];

  // workspace layout: sg16 [2][225][8] f32 (14400 B) | qkvw1 f16 (393216 B) |
  // qkvw2 f16 | pw1 f16 (131072 B) | pw2 f16  -> total ~1.04 MB
  float* SG16 = (float*)d_ws;
  f16* wq1f = (f16*)((char*)d_ws + 14400);
  f16* wq2f = wq1f + 196608;
  f16* pw1f = wq2f + 196608;
  f16* pw2f = pw1f + 65536;
  float* out = (float*)d_out;

  prep_all<<<706, 256, 0, stream>>>(cw11, cb11, cw12, cw21, cb21, cw22,
                                    qkvw1, qkvw2, pw1, pw2,
                                    SG16, wq1f, wq2f, pw1f, pw2f);
  fused_attn<<<NWIN, 512, 0, stream>>>(x1, x2,
      wq1f, qb1, vb1, wq2f, qb2, vb2,
      pcw1, pcb1, ls1, pcw2, pcb2, ls2,
      pw1f, pb1, pw2f, pb2, SG16, out);
}

// Round 6
// 292.956 us; speedup vs baseline: 1.6397x; 1.0280x over previous
//
#include <hip/hip_runtime.h>

typedef _Float16 f16;
typedef f16  f16x8  __attribute__((ext_vector_type(8)));
typedef f16  f16x4v __attribute__((ext_vector_type(4)));
typedef f16  f16x2  __attribute__((ext_vector_type(2)));
typedef float f32x4 __attribute__((ext_vector_type(4)));

#define MFMA_F16(a,b,c) __builtin_amdgcn_mfma_f32_16x16x32_f16((a),(b),(c),0,0,0)

#define NWIN 512
// Sb: [16 qrows][64 k][8 dwords + 16B pad] — each dword = f16x2 (same,diff)
// score pair for one head. Row stride 3088 B (== R3's proven stride: ≡16 mod
// 128 so the b128 reads spread m&7 over 8 slots; k-slot stride 48 B spreads
// m&7 on writes). NO XOR swizzle: R4/R5's XOR collided because rows are not
// 128-aligned (verified counterexample qrow=2: (k=15,ch8) and (k=16,ch8) both
// -> phys 6928). b32 packing halves write-instruction count vs R3's scalar
// b16 writes; numerics identical (same f16 RNE casts).
#define SB_QST 3088
#define SB_KST 48
// full-x staging: [64 tok][256 + 8 pad] f16 (528 B row)
#define BUFX_ST 264
// per-head QKV output scratch: Q/K swizzled [64][32] (4096 B), V transposed [32][72]
#define BUFO_HEAD 2304
#define VT_ST 72
// sm layout: bufX [0,33792) | bufO [33792,70656)
// attention reuse: Sb [0,49408) | sTbl [49408,63808)
#define SM_BYTES 70656
#define STBL_OFF 49408

// load 8 consecutive fp32, round to f16x8
__device__ __forceinline__ f16x8 ld_f16x8(const float* __restrict__ p) {
  f32x4 a = *(const f32x4*)p;
  f32x4 b = *(const f32x4*)(p + 4);
  f16x8 r;
  r[0] = (f16)a[0]; r[1] = (f16)a[1]; r[2] = (f16)a[2]; r[3] = (f16)a[3];
  r[4] = (f16)b[0]; r[5] = (f16)b[1]; r[6] = (f16)b[2]; r[7] = (f16)b[3];
  return r;
}

// ---------------- prep: CPB MLP table + weight f32->f16 conversion ----------
__global__ __launch_bounds__(256) void prep_all(
    const float* __restrict__ w1a, const float* __restrict__ b1a,
    const float* __restrict__ w2a,
    const float* __restrict__ w1b, const float* __restrict__ b1b,
    const float* __restrict__ w2b,
    const float* __restrict__ qkvw1, const float* __restrict__ qkvw2,
    const float* __restrict__ pw1, const float* __restrict__ pw2,
    float* __restrict__ sg16,
    f16* __restrict__ wq1f, f16* __restrict__ wq2f,
    f16* __restrict__ pw1f, f16* __restrict__ pw2f) {
  const int b = blockIdx.x;
  if (b >= 450) {
    const int cb = b - 450;
    const float* src; f16* dst; int base;
    if (cb < 96)       { src = qkvw1; dst = wq1f; base = cb * 2048; }
    else if (cb < 192) { src = qkvw2; dst = wq2f; base = (cb - 96) * 2048; }
    else if (cb < 224) { src = pw1;   dst = pw1f; base = (cb - 192) * 2048; }
    else               { src = pw2;   dst = pw2f; base = (cb - 224) * 2048; }
    const int o = base + threadIdx.x * 8;
    *(f16x8*)(dst + o) = ld_f16x8(src + o);
    return;
  }
  const int view = b / 225;
  const int e    = b % 225;
  const float* __restrict__ w1 = view ? w1b : w1a;
  const float* __restrict__ b1 = view ? b1b : b1a;
  const float* __restrict__ w2 = view ? w2b : w2a;
  const int t = threadIdx.x;
  const int i = e / 15, j = e % 15;
  const float vi = 8.0f * (float)(i - 7) * (1.0f / 7.0f);
  const float vj = 8.0f * (float)(j - 7) * (1.0f / 7.0f);
  const float in0 = copysignf(log2f(fabsf(vi) + 1.0f) * (1.0f / 3.0f), vi);
  const float in1 = copysignf(log2f(fabsf(vj) + 1.0f) * (1.0f / 3.0f), vj);
  float acc[8] = {0.f,0.f,0.f,0.f,0.f,0.f,0.f,0.f};
#pragma unroll
  for (int uu = 0; uu < 2; ++uu) {
    const int u = t + uu * 256;
    float hv = fmaxf(w1[2*u] * in0 + w1[2*u+1] * in1 + b1[u], 0.0f);
#pragma unroll
    for (int hh = 0; hh < 8; ++hh) acc[hh] += w2[hh*512 + u] * hv;
  }
#pragma unroll
  for (int off = 32; off >= 1; off >>= 1)
#pragma unroll
    for (int hh = 0; hh < 8; ++hh) acc[hh] += __shfl_xor(acc[hh], off, 64);
  __shared__ float red[4][8];
  if ((t & 63) == 0) {
#pragma unroll
    for (int hh = 0; hh < 8; ++hh) red[t >> 6][hh] = acc[hh];
  }
  __syncthreads();
  if (t < 8) {
    float s = red[0][t] + red[1][t] + red[2][t] + red[3][t];
    sg16[(view * 225 + e) * 8 + t] = 16.0f / (1.0f + __expf(-s));
  }
}

// ---------------- fused: per-window (both views) QKV + attention + proj ------
// launch_bounds (512, 2): LDS caps at 2 blocks/CU; asking 4 (R2) forced
// VGPR=64 -> ~350 MB scratch spill. 2 -> 128 VGPR, no spill.
__global__ __launch_bounds__(512, 2) void fused_attn(
    const float* __restrict__ x1, const float* __restrict__ x2,
    const f16* __restrict__ qkvw1, const float* __restrict__ qb1, const float* __restrict__ vb1,
    const f16* __restrict__ qkvw2, const float* __restrict__ qb2, const float* __restrict__ vb2,
    const float* __restrict__ pcw1, const float* __restrict__ pcb1, const float* __restrict__ ls1,
    const float* __restrict__ pcw2, const float* __restrict__ pcb2, const float* __restrict__ ls2,
    const f16* __restrict__ pw1, const float* __restrict__ pb1,
    const f16* __restrict__ pw2, const float* __restrict__ pb2,
    const float* __restrict__ sg16,
    float* __restrict__ outp) {
  const int win = blockIdx.x;
  const int tid = threadIdx.x;
  const int lane = tid & 63, h = tid >> 6;
  const int quad = lane >> 4, m = lane & 15;

  __shared__ __align__(16) char sm[SM_BYTES];
  f16* bufX  = (f16*)sm;
  f16* bufO  = (f16*)(sm + 33792);
  char* Sbc  = sm;                    // Sb accessed via byte addresses
  f16* preB  = (f16*)sm;
  float* sTbl = (float*)(sm + STBL_OFF);

  const f32x4 z4 = {0.f, 0.f, 0.f, 0.f};
  f16x8 aqF[2][4], kfF[2][4], bvF[2][2][2];
  f16* oh = bufO + h * BUFO_HEAD;

  // ================= QKV GEMMs, both views =================
  for (int view = 0; view < 2; ++view) {
    const float* __restrict__ xv = (view ? x2 : x1) + (size_t)win * (64 * 256);
    const f16* __restrict__ W    = view ? qkvw2 : qkvw1;
    const float* __restrict__ qb = view ? qb2 : qb1;
    const float* __restrict__ vb = view ? vb2 : vb1;

    __syncthreads();   // bufX/bufO safe to overwrite (prev view's reads done)
    for (int i = tid; i < 2048; i += 512) {           // 64 rows x 32 chunks of 8
      const int row = i >> 5, c8 = i & 31;
      *(f16x8*)(bufX + row * BUFX_ST + c8 * 8) = ld_f16x8(xv + row * 256 + c8 * 8);
    }
    __syncthreads();   // bufX ready (stable for all 3 secs)

    for (int sec = 0; sec < 3; ++sec) {
      f32x4 acc0[4], acc1[4];
#pragma unroll
      for (int t = 0; t < 4; ++t) { acc0[t] = z4; acc1[t] = z4; }
      const f16* wb = W + (size_t)(sec * 256 + h * 32) * 256 + quad * 8;
#pragma unroll 2
      for (int k8 = 0; k8 < 8; ++k8) {
        f16x8 a0 = *(const f16x8*)(wb + (size_t)m * 256 + k8 * 32);
        f16x8 a1 = *(const f16x8*)(wb + (size_t)(16 + m) * 256 + k8 * 32);
#pragma unroll
        for (int tt = 0; tt < 4; ++tt) {
          f16x8 bfr = *(const f16x8*)(bufX + (tt * 16 + m) * BUFX_ST + k8 * 32 + quad * 8);
          acc0[tt] = MFMA_F16(a0, bfr, acc0[tt]);
          acc1[tt] = MFMA_F16(a1, bfr, acc1[tt]);
        }
      }
      // epilogue: bias, (l2norm q/k), write to own head's bufO region.
      float bs0[4], bs1[4];
#pragma unroll
      for (int r = 0; r < 4; ++r) {
        int c0 = h * 32 + quad * 4 + r;
        bs0[r] = (sec == 0) ? qb[c0] : (sec == 2 ? vb[c0] : 0.f);
        bs1[r] = (sec == 0) ? qb[c0 + 16] : (sec == 2 ? vb[c0 + 16] : 0.f);
      }
#pragma unroll
      for (int tt = 0; tt < 4; ++tt) {
        float v0[4], v1[4];
#pragma unroll
        for (int r = 0; r < 4; ++r) { v0[r] = acc0[tt][r] + bs0[r]; v1[r] = acc1[tt][r] + bs1[r]; }
        if (sec < 2) {
          float ss = 0.f;
#pragma unroll
          for (int r = 0; r < 4; ++r) ss += v0[r] * v0[r] + v1[r] * v1[r];
          ss += __shfl_xor(ss, 16, 64);
          ss += __shfl_xor(ss, 32, 64);
          float s = 1.0f / fmaxf(sqrtf(ss), 1e-12f);
#pragma unroll
          for (int r = 0; r < 4; ++r) { v0[r] *= s; v1[r] *= s; }
        }
        const int n = tt * 16 + m;
        if (sec < 2) {
          // Q/K: swizzled [tok][32ch] layout; XOR of byte bits 4-6 with (n&7)
          // is bijective here because rows ARE 64B-strided within the 4KB
          // region and the XOR stays inside the row's 128B window pair.
          f16x4v p0, p1;
#pragma unroll
          for (int r = 0; r < 4; ++r) { p0[r] = (f16)v0[r]; p1[r] = (f16)v1[r]; }
          char* ob = (char*)oh;
          const int sw = (n & 7) << 4;
          *(f16x4v*)(ob + ((n * 64 + quad * 8) ^ sw))      = p0;
          *(f16x4v*)(ob + ((n * 64 + 32 + quad * 8) ^ sw)) = p1;
        } else {
          // V: store transposed Vt[ch][tok] so fragment reads are vector loads
#pragma unroll
          for (int r = 0; r < 4; ++r) {
            oh[(quad * 4 + r) * VT_ST + n]      = (f16)v0[r];
            oh[(quad * 4 + 16 + r) * VT_ST + n] = (f16)v1[r];
          }
        }
      }
      // fragment extraction — own-head region only, no barrier needed
      if (sec == 0) {
#pragma unroll
        for (int rt = 0; rt < 4; ++rt) {
          const int n = rt * 16 + m;
          aqF[view][rt] = *(const f16x8*)((char*)oh + ((n * 64 + quad * 16) ^ ((n & 7) << 4)));
        }
      } else if (sec == 1) {
#pragma unroll
        for (int ct = 0; ct < 4; ++ct) {
          const int n = ct * 16 + m;
          kfF[view][ct] = *(const f16x8*)((char*)oh + ((n * 64 + quad * 16) ^ ((n & 7) << 4)));
        }
      } else {
#pragma unroll
        for (int nt = 0; nt < 2; ++nt)
#pragma unroll
          for (int kv = 0; kv < 2; ++kv)
            bvF[view][nt][kv] = *(const f16x8*)(oh + (nt * 16 + m) * VT_ST + kv * 32 + quad * 8);
      }
    }
  }
  __syncthreads();   // all fragments in regs; sm free for Sb/sTbl

  // load bias table once for BOTH views
  for (int i = tid; i < 3600; i += 512) sTbl[i] = sg16[i];

  // ================= attention + proj, both views =================
#pragma unroll
  for (int view = 0; view < 2; ++view) {
    const float* __restrict__ pcw = view ? pcw2 : pcw1;
    float pcwf[16];
#pragma unroll
    for (int c = 0; c < 16; ++c) pcwf[c] = pcw[h * 16 + c];
    const float pcb_h = (view ? pcb2 : pcb1)[h];
    const float lsv = (view ? ls2 : ls1)[h];
    const float scale_h = __expf(fminf(lsv, 4.6051702f));
    const float pcbs = pcb_h * scale_h;
    const float* tblv = sTbl + view * 1800;

    f32x4 oacc[4][2];
#pragma unroll
    for (int rt = 0; rt < 4; ++rt) {
      f16x8 aq = aqF[view][rt];
      // Score MFMAs (setprio: favor the MFMA-issuing wave vs the co-resident
      // block's memory-phase waves). Pack (same,diff) per head into one dword
      // -> 16 ds_write_b32 per rt (was 32 scalar b16): write conflicts halve.
      __builtin_amdgcn_s_setprio(1);
#pragma unroll
      for (int ct = 0; ct < 4; ++ct) {
        const int kk = ct * 16 + m;
        const int wbase = kk * SB_KST + (h << 2);
        f32x4 Ss = MFMA_F16(aq, kfF[view][ct], z4);
        f32x4 Sd = MFMA_F16(aq, kfF[1 - view][ct], z4);
#pragma unroll
        for (int r = 0; r < 4; ++r) {
          f16x2 pr; pr[0] = (f16)Ss[r]; pr[1] = (f16)Sd[r];
          *(f16x2*)(Sbc + (quad * 4 + r) * SB_QST + wbase) = pr;
        }
      }
      __builtin_amdgcn_s_setprio(0);
      __syncthreads();   // B1: Sb complete (all heads' channels)

      // ---- logits: 16-channel mix from packed Sb; softmax; AV ----
      const int n = rt * 16 + m;
      const int nh_ = n >> 3, nw_ = n & 7;
      const int rbase = m * SB_QST;
      float logit[16];
#pragma unroll
      for (int j = 0; j < 16; ++j) {
        const int mm = (j < 8) ? (quad * 8 + j) : (32 + quad * 8 + (j - 8));
        const int b0 = rbase + mm * SB_KST;
        f16x8 s0 = *(const f16x8*)(Sbc + b0);        // heads 0-3: (s,d) pairs
        f16x8 s1 = *(const f16x8*)(Sbc + b0 + 16);   // heads 4-7
        float mix = 0.f;
#pragma unroll
        for (int c = 0; c < 4; ++c) {
          mix += pcwf[c]      * (float)s0[2*c] + pcwf[8 + c]  * (float)s0[2*c+1];
          mix += pcwf[4 + c]  * (float)s1[2*c] + pcwf[12 + c] * (float)s1[2*c+1];
        }
        const int idx = (nh_ - (mm >> 3) + 7) * 15 + (nw_ - (mm & 7) + 7);
        logit[j] = mix * scale_h + pcbs + tblv[idx * 8 + h];
      }
      float mx = -1e30f;
#pragma unroll
      for (int j = 0; j < 16; ++j) mx = fmaxf(mx, logit[j]);
      mx = fmaxf(mx, __shfl_xor(mx, 16, 64));
      mx = fmaxf(mx, __shfl_xor(mx, 32, 64));
      float p[16], sum = 0.f;
#pragma unroll
      for (int j = 0; j < 16; ++j) { p[j] = __expf(logit[j] - mx); sum += p[j]; }
      sum += __shfl_xor(sum, 16, 64);
      sum += __shfl_xor(sum, 32, 64);
      float inv = 1.0f / sum;
      f16x8 av0, av1;
#pragma unroll
      for (int j = 0; j < 8; ++j) { av0[j] = (f16)(p[j] * inv); av1[j] = (f16)(p[8 + j] * inv); }
      __builtin_amdgcn_s_setprio(1);
#pragma unroll
      for (int nt = 0; nt < 2; ++nt) {
        f32x4 z = z4;
        z = MFMA_F16(av0, bvF[view][nt][0], z);
        z = MFMA_F16(av1, bvF[view][nt][1], z);
        oacc[rt][nt] = z;
      }
      __builtin_amdgcn_s_setprio(0);
      __syncthreads();   // B2: Sb reads done before next rt overwrites
    }

    // ---- pre-projection activations -> preB ----
#pragma unroll
    for (int mt = 0; mt < 4; ++mt)
#pragma unroll
      for (int nt = 0; nt < 2; ++nt)
#pragma unroll
        for (int r = 0; r < 4; ++r)
          preB[(mt * 16 + quad * 4 + r) * 264 + h * 32 + nt * 16 + m] = (f16)oacc[mt][nt][r];
    __syncthreads();   // preB ready

    // ---- proj GEMM from preB (f16 weights) ----
    const f16* __restrict__ Wp = view ? pw2 : pw1;
    const float* __restrict__ pb = view ? pb2 : pb1;
    f32x4 pacc0[4], pacc1[4];
#pragma unroll
    for (int t = 0; t < 4; ++t) { pacc0[t] = z4; pacc1[t] = z4; }
#pragma unroll 2
    for (int ks = 0; ks < 8; ++ks) {
      f16x8 pa0 = *(const f16x8*)(Wp + (size_t)(h * 32 + m) * 256 + ks * 32 + quad * 8);
      f16x8 pa1 = *(const f16x8*)(Wp + (size_t)(h * 32 + 16 + m) * 256 + ks * 32 + quad * 8);
#pragma unroll
      for (int tt = 0; tt < 4; ++tt) {
        f16x8 bfr = *(const f16x8*)(preB + (tt * 16 + m) * 264 + ks * 32 + quad * 8);
        pacc0[tt] = MFMA_F16(pa0, bfr, pacc0[tt]);
        pacc1[tt] = MFMA_F16(pa1, bfr, pacc1[tt]);
      }
    }
    // ---- FP32 output store ----
    float* obase = outp + (size_t)(view * NWIN + win) * (64 * 256);
#pragma unroll
    for (int tt = 0; tt < 4; ++tt) {
      f32x4 p0, p1;
#pragma unroll
      for (int r = 0; r < 4; ++r) {
        p0[r] = pacc0[tt][r] + pb[h * 32 + quad * 4 + r];
        p1[r] = pacc1[tt][r] + pb[h * 32 + 16 + quad * 4 + r];
      }
      const int n = tt * 16 + m;
      *(f32x4*)(obase + n * 256 + h * 32 + quad * 4)      = p0;
      *(f32x4*)(obase + n * 256 + h * 32 + 16 + quad * 4) = p1;
    }
    __syncthreads();   // preB/Sb reads done before next view reuses sm
  }
}

extern "C" void kernel_launch(void* const* d_in, const int* in_sizes, int n_in,
                              void* d_out, int out_size, void* d_ws, size_t ws_size,
                              hipStream_t stream) {
  (void)in_sizes; (void)n_in; (void)out_size; (void)ws_size;
  const float* x1   = (const float*)d_in[0];
  const float* x2   = (const float*)d_in[1];
  const float* qkvw1= (const float*)d_in[2];
  const float* qb1  = (const float*)d_in[3];
  const float* vb1  = (const float*)d_in[4];
  const float* pw1  = (const float*)d_in[5];
  const float* pb1  = (const float*)d_in[6];
  const float* ls1  = (const float*)d_in[7];
  const float* cw11 = (const float*)d_in[8];
  const float* cb11 = (const float*)d_in[9];
  const float* cw12 = (const float*)d_in[10];
  const float* pcw1 = (const float*)d_in[11];
  const float* pcb1 = (const float*)d_in[12];
  const float* qkvw2= (const float*)d_in[13];
  const float* qb2  = (const float*)d_in[14];
  const float* vb2  = (const float*)d_in[15];
  const float* pw2  = (const float*)d_in[16];
  const float* pb2  = (const float*)d_in[17];
  const float* ls2  = (const float*)d_in[18];
  const float* cw21 = (const float*)d_in[19];
  const float* cb21 = (const float*)d_in[20];
  const float* cw22 = (const float*)d_in[21];
  const float* pcw2 = (const float*)d_in[22];
  const float* pcb2 = (const float*)d_in[23];

  // workspace: sg16 [2][225][8] f32 (14400 B) | qkvw1 f16 | qkvw2 f16 |
  // pw1 f16 | pw2 f16  -> ~1.04 MB
  float* SG16 = (float*)d_ws;
  f16* wq1f = (f16*)((char*)d_ws + 14400);
  f16* wq2f = wq1f + 196608;
  f16* pw1f = wq2f + 196608;
  f16* pw2f = pw1f + 65536;
  float* out = (float*)d_out;

  prep_all<<<706, 256, 0, stream>>>(cw11, cb11, cw12, cw21, cb21, cw22,
                                    qkvw1, qkvw2, pw1, pw2,
                                    SG16, wq1f, wq2f, pw1f, pw2f);
  fused_attn<<<NWIN, 512, 0, stream>>>(x1, x2,
      wq1f, qb1, vb1, wq2f, qb2, vb2,
      pcw1, pcb1, ls1, pcw2, pcb2, ls2,
      pw1f, pb1, pw2f, pb2, SG16, out);
}

// Round 7
// 277.921 us; speedup vs baseline: 1.7284x; 1.0541x over previous
//
#include <hip/hip_runtime.h>

typedef _Float16 f16;
typedef f16  f16x8  __attribute__((ext_vector_type(8)));
typedef f16  f16x4v __attribute__((ext_vector_type(4)));
typedef f16  f16x2  __attribute__((ext_vector_type(2)));
typedef float f32x4 __attribute__((ext_vector_type(4)));

#define MFMA_F16(a,b,c) __builtin_amdgcn_mfma_f32_16x16x32_f16((a),(b),(c),0,0,0)

#define NWIN 512
// Sb: [16 qrows][64 k][8 dwords + 16B pad] — each dword = f16x2 (same,diff)
// score pair for one head. Row stride 3088 B (≡16 mod 128 so b128 reads
// spread m&7 over 8 slots; 48 B k-slot spreads writes). NO XOR swizzle
// (R4/R5's XOR collided: rows not 128-aligned).
#define SB_QST 3088
#define SB_KST 48
// full-x staging: [64 tok][256 + 8 pad] f16 (528 B row)
#define BUFX_ST 264
// per-head QKV output scratch: Q/K swizzled [64][32] (4096 B), V transposed [32][72]
#define BUFO_HEAD 2304
#define VT_ST 72
// sm layout: bufX [0,33792) | bufO [33792,70656)
// attention reuse: Sb [0,49408) | sTbl [49408,63808)
#define SM_BYTES 70656
#define STBL_OFF 49408

// load 8 consecutive fp32, round to f16x8
__device__ __forceinline__ f16x8 ld_f16x8(const float* __restrict__ p) {
  f32x4 a = *(const f32x4*)p;
  f32x4 b = *(const f32x4*)(p + 4);
  f16x8 r;
  r[0] = (f16)a[0]; r[1] = (f16)a[1]; r[2] = (f16)a[2]; r[3] = (f16)a[3];
  r[4] = (f16)b[0]; r[5] = (f16)b[1]; r[6] = (f16)b[2]; r[7] = (f16)b[3];
  return r;
}

// ---------------- prep: CPB MLP table + weight f32->f16 conversion ----------
__global__ __launch_bounds__(256) void prep_all(
    const float* __restrict__ w1a, const float* __restrict__ b1a,
    const float* __restrict__ w2a,
    const float* __restrict__ w1b, const float* __restrict__ b1b,
    const float* __restrict__ w2b,
    const float* __restrict__ qkvw1, const float* __restrict__ qkvw2,
    const float* __restrict__ pw1, const float* __restrict__ pw2,
    float* __restrict__ sg16,
    f16* __restrict__ wq1f, f16* __restrict__ wq2f,
    f16* __restrict__ pw1f, f16* __restrict__ pw2f) {
  const int b = blockIdx.x;
  if (b >= 450) {
    const int cb = b - 450;
    const float* src; f16* dst; int base;
    if (cb < 96)       { src = qkvw1; dst = wq1f; base = cb * 2048; }
    else if (cb < 192) { src = qkvw2; dst = wq2f; base = (cb - 96) * 2048; }
    else if (cb < 224) { src = pw1;   dst = pw1f; base = (cb - 192) * 2048; }
    else               { src = pw2;   dst = pw2f; base = (cb - 224) * 2048; }
    const int o = base + threadIdx.x * 8;
    *(f16x8*)(dst + o) = ld_f16x8(src + o);
    return;
  }
  const int view = b / 225;
  const int e    = b % 225;
  const float* __restrict__ w1 = view ? w1b : w1a;
  const float* __restrict__ b1 = view ? b1b : b1a;
  const float* __restrict__ w2 = view ? w2b : w2a;
  const int t = threadIdx.x;
  const int i = e / 15, j = e % 15;
  const float vi = 8.0f * (float)(i - 7) * (1.0f / 7.0f);
  const float vj = 8.0f * (float)(j - 7) * (1.0f / 7.0f);
  const float in0 = copysignf(log2f(fabsf(vi) + 1.0f) * (1.0f / 3.0f), vi);
  const float in1 = copysignf(log2f(fabsf(vj) + 1.0f) * (1.0f / 3.0f), vj);
  float acc[8] = {0.f,0.f,0.f,0.f,0.f,0.f,0.f,0.f};
#pragma unroll
  for (int uu = 0; uu < 2; ++uu) {
    const int u = t + uu * 256;
    float hv = fmaxf(w1[2*u] * in0 + w1[2*u+1] * in1 + b1[u], 0.0f);
#pragma unroll
    for (int hh = 0; hh < 8; ++hh) acc[hh] += w2[hh*512 + u] * hv;
  }
#pragma unroll
  for (int off = 32; off >= 1; off >>= 1)
#pragma unroll
    for (int hh = 0; hh < 8; ++hh) acc[hh] += __shfl_xor(acc[hh], off, 64);
  __shared__ float red[4][8];
  if ((t & 63) == 0) {
#pragma unroll
    for (int hh = 0; hh < 8; ++hh) red[t >> 6][hh] = acc[hh];
  }
  __syncthreads();
  if (t < 8) {
    float s = red[0][t] + red[1][t] + red[2][t] + red[3][t];
    sg16[(view * 225 + e) * 8 + t] = 16.0f / (1.0f + __expf(-s));
  }
}

// ---------------- fused: per-window (both views) QKV + attention + proj ------
// launch_bounds (512, 2): LDS caps at 2 blocks/CU; asking 4 (R2) forced
// VGPR=64 -> ~350 MB scratch spill. 2 -> 128 VGPR, no spill.
__global__ __launch_bounds__(512, 2) void fused_attn(
    const float* __restrict__ x1, const float* __restrict__ x2,
    const f16* __restrict__ qkvw1, const float* __restrict__ qb1, const float* __restrict__ vb1,
    const f16* __restrict__ qkvw2, const float* __restrict__ qb2, const float* __restrict__ vb2,
    const float* __restrict__ pcw1, const float* __restrict__ pcb1, const float* __restrict__ ls1,
    const float* __restrict__ pcw2, const float* __restrict__ pcb2, const float* __restrict__ ls2,
    const f16* __restrict__ pw1, const float* __restrict__ pb1,
    const f16* __restrict__ pw2, const float* __restrict__ pb2,
    const float* __restrict__ sg16,
    float* __restrict__ outp) {
  const int win = blockIdx.x;
  const int tid = threadIdx.x;
  const int lane = tid & 63, h = tid >> 6;
  const int quad = lane >> 4, m = lane & 15;

  __shared__ __align__(16) char sm[SM_BYTES];
  f16* bufX  = (f16*)sm;
  f16* bufO  = (f16*)(sm + 33792);
  char* Sbc  = sm;                    // Sb accessed via byte addresses
  f16* preB  = (f16*)sm;
  float* sTbl = (float*)(sm + STBL_OFF);

  const f32x4 z4 = {0.f, 0.f, 0.f, 0.f};
  f16x8 aqF[2][4], kfF[2][4], bvF[2][2][2];
  f16* oh = bufO + h * BUFO_HEAD;

  // ================= QKV GEMMs, both views =================
  for (int view = 0; view < 2; ++view) {
    const float* __restrict__ xv = (view ? x2 : x1) + (size_t)win * (64 * 256);
    const f16* __restrict__ W    = view ? qkvw2 : qkvw1;
    const float* __restrict__ qb = view ? qb2 : qb1;
    const float* __restrict__ vb = view ? vb2 : vb1;

    __syncthreads();   // bufX/bufO safe to overwrite (prev view's reads done)
    for (int i = tid; i < 2048; i += 512) {           // 64 rows x 32 chunks of 8
      const int row = i >> 5, c8 = i & 31;
      *(f16x8*)(bufX + row * BUFX_ST + c8 * 8) = ld_f16x8(xv + row * 256 + c8 * 8);
    }
    __syncthreads();   // bufX ready (stable for all 3 secs)

    for (int sec = 0; sec < 3; ++sec) {
      f32x4 acc0[4], acc1[4];
#pragma unroll
      for (int t = 0; t < 4; ++t) { acc0[t] = z4; acc1[t] = z4; }
      const f16* wb = W + (size_t)(sec * 256 + h * 32) * 256 + quad * 8;
#pragma unroll 2
      for (int k8 = 0; k8 < 8; ++k8) {
        f16x8 a0 = *(const f16x8*)(wb + (size_t)m * 256 + k8 * 32);
        f16x8 a1 = *(const f16x8*)(wb + (size_t)(16 + m) * 256 + k8 * 32);
#pragma unroll
        for (int tt = 0; tt < 4; ++tt) {
          f16x8 bfr = *(const f16x8*)(bufX + (tt * 16 + m) * BUFX_ST + k8 * 32 + quad * 8);
          acc0[tt] = MFMA_F16(a0, bfr, acc0[tt]);
          acc1[tt] = MFMA_F16(a1, bfr, acc1[tt]);
        }
      }
      // epilogue: bias, (l2norm q/k), write to own head's bufO region.
      float bs0[4], bs1[4];
#pragma unroll
      for (int r = 0; r < 4; ++r) {
        int c0 = h * 32 + quad * 4 + r;
        bs0[r] = (sec == 0) ? qb[c0] : (sec == 2 ? vb[c0] : 0.f);
        bs1[r] = (sec == 0) ? qb[c0 + 16] : (sec == 2 ? vb[c0 + 16] : 0.f);
      }
#pragma unroll
      for (int tt = 0; tt < 4; ++tt) {
        float v0[4], v1[4];
#pragma unroll
        for (int r = 0; r < 4; ++r) { v0[r] = acc0[tt][r] + bs0[r]; v1[r] = acc1[tt][r] + bs1[r]; }
        if (sec < 2) {
          float ss = 0.f;
#pragma unroll
          for (int r = 0; r < 4; ++r) ss += v0[r] * v0[r] + v1[r] * v1[r];
          ss += __shfl_xor(ss, 16, 64);
          ss += __shfl_xor(ss, 32, 64);
          float s = 1.0f / fmaxf(sqrtf(ss), 1e-12f);
#pragma unroll
          for (int r = 0; r < 4; ++r) { v0[r] *= s; v1[r] *= s; }
        }
        const int n = tt * 16 + m;
        if (sec < 2) {
          // Q/K: swizzled [tok][32ch] layout (bijective within 64B rows)
          f16x4v p0, p1;
#pragma unroll
          for (int r = 0; r < 4; ++r) { p0[r] = (f16)v0[r]; p1[r] = (f16)v1[r]; }
          char* ob = (char*)oh;
          const int sw = (n & 7) << 4;
          *(f16x4v*)(ob + ((n * 64 + quad * 8) ^ sw))      = p0;
          *(f16x4v*)(ob + ((n * 64 + 32 + quad * 8) ^ sw)) = p1;
        } else {
          // V: store transposed Vt[ch][tok] so fragment reads are vector loads
#pragma unroll
          for (int r = 0; r < 4; ++r) {
            oh[(quad * 4 + r) * VT_ST + n]      = (f16)v0[r];
            oh[(quad * 4 + 16 + r) * VT_ST + n] = (f16)v1[r];
          }
        }
      }
      // fragment extraction — own-head region only, no barrier needed
      if (sec == 0) {
#pragma unroll
        for (int rt = 0; rt < 4; ++rt) {
          const int n = rt * 16 + m;
          aqF[view][rt] = *(const f16x8*)((char*)oh + ((n * 64 + quad * 16) ^ ((n & 7) << 4)));
        }
      } else if (sec == 1) {
#pragma unroll
        for (int ct = 0; ct < 4; ++ct) {
          const int n = ct * 16 + m;
          kfF[view][ct] = *(const f16x8*)((char*)oh + ((n * 64 + quad * 16) ^ ((n & 7) << 4)));
        }
      } else {
#pragma unroll
        for (int nt = 0; nt < 2; ++nt)
#pragma unroll
          for (int kv = 0; kv < 2; ++kv)
            bvF[view][nt][kv] = *(const f16x8*)(oh + (nt * 16 + m) * VT_ST + kv * 32 + quad * 8);
      }
    }
  }
  __syncthreads();   // all fragments in regs; sm free for Sb/sTbl

  // load bias table once for BOTH views
  for (int i = tid; i < 3600; i += 512) sTbl[i] = sg16[i];

  // ================= attention + proj, both views =================
#pragma unroll
  for (int view = 0; view < 2; ++view) {
    const float* __restrict__ pcw = view ? pcw2 : pcw1;
    // fdot2 weight pairs matched to Sb's (same,diff) dword packing:
    // s0 dword c (c=0..3) = (S_same[head c], S_diff[head c]) -> w0[c]=(pcw[c],pcw[8+c])
    // s1 dword c          = heads 4..7                        -> w1[c]=(pcw[4+c],pcw[12+c])
    // Precision: S already f16 in Sb (no new rounding); only pcw (~0.1) gets
    // f16 rounding -> ~1e-3 logit err at scale 10 -> ~3e-4 output err.
    f16x2 w0[4], w1[4];
#pragma unroll
    for (int c = 0; c < 4; ++c) {
      f16x2 a, b;
      a[0] = (f16)pcw[h * 16 + c];     a[1] = (f16)pcw[h * 16 + 8 + c];
      b[0] = (f16)pcw[h * 16 + 4 + c]; b[1] = (f16)pcw[h * 16 + 12 + c];
      w0[c] = a; w1[c] = b;
    }
    const float pcb_h = (view ? pcb2 : pcb1)[h];
    const float lsv = (view ? ls2 : ls1)[h];
    const float scale_h = __expf(fminf(lsv, 4.6051702f));
    const float pcbs = pcb_h * scale_h;
    const float* tblv = sTbl + view * 1800;

    f32x4 oacc[4][2];
#pragma unroll
    for (int rt = 0; rt < 4; ++rt) {
      f16x8 aq = aqF[view][rt];
      // Score MFMAs; pack (same,diff) per head into one dword -> ds_write_b32.
      __builtin_amdgcn_s_setprio(1);
#pragma unroll
      for (int ct = 0; ct < 4; ++ct) {
        const int kk = ct * 16 + m;
        const int wbase = kk * SB_KST + (h << 2);
        f32x4 Ss = MFMA_F16(aq, kfF[view][ct], z4);
        f32x4 Sd = MFMA_F16(aq, kfF[1 - view][ct], z4);
#pragma unroll
        for (int r = 0; r < 4; ++r) {
          f16x2 pr; pr[0] = (f16)Ss[r]; pr[1] = (f16)Sd[r];
          *(f16x2*)(Sbc + (quad * 4 + r) * SB_QST + wbase) = pr;
        }
      }
      __builtin_amdgcn_s_setprio(0);
      __syncthreads();   // B1: Sb complete (all heads' channels)

      // ---- logits: 16-ch mix via v_dot2_f32_f16; softmax; AV ----
      const int n = rt * 16 + m;
      const int nh_ = n >> 3, nw_ = n & 7;
      const int rbase = m * SB_QST;
      float logit[16];
#pragma unroll
      for (int j = 0; j < 16; ++j) {
        const int mm = (j < 8) ? (quad * 8 + j) : (32 + quad * 8 + (j - 8));
        const int b0 = rbase + mm * SB_KST;
        f16x8 s0 = *(const f16x8*)(Sbc + b0);        // heads 0-3: (s,d) pairs
        f16x8 s1 = *(const f16x8*)(Sbc + b0 + 16);   // heads 4-7
        const f16x2* s0p = (const f16x2*)&s0;
        const f16x2* s1p = (const f16x2*)&s1;
        float mix = 0.f;
#pragma unroll
        for (int c = 0; c < 4; ++c) {
          mix = __builtin_amdgcn_fdot2(s0p[c], w0[c], mix, false);
          mix = __builtin_amdgcn_fdot2(s1p[c], w1[c], mix, false);
        }
        const int idx = (nh_ - (mm >> 3) + 7) * 15 + (nw_ - (mm & 7) + 7);
        logit[j] = mix * scale_h + pcbs + tblv[idx * 8 + h];
      }
      float mx = -1e30f;
#pragma unroll
      for (int j = 0; j < 16; ++j) mx = fmaxf(mx, logit[j]);
      mx = fmaxf(mx, __shfl_xor(mx, 16, 64));
      mx = fmaxf(mx, __shfl_xor(mx, 32, 64));
      float p[16], sum = 0.f;
#pragma unroll
      for (int j = 0; j < 16; ++j) { p[j] = __expf(logit[j] - mx); sum += p[j]; }
      sum += __shfl_xor(sum, 16, 64);
      sum += __shfl_xor(sum, 32, 64);
      float inv = 1.0f / sum;
      f16x8 av0, av1;
#pragma unroll
      for (int j = 0; j < 8; ++j) { av0[j] = (f16)(p[j] * inv); av1[j] = (f16)(p[8 + j] * inv); }
      __builtin_amdgcn_s_setprio(1);
#pragma unroll
      for (int nt = 0; nt < 2; ++nt) {
        f32x4 z = z4;
        z = MFMA_F16(av0, bvF[view][nt][0], z);
        z = MFMA_F16(av1, bvF[view][nt][1], z);
        oacc[rt][nt] = z;
      }
      __builtin_amdgcn_s_setprio(0);
      __syncthreads();   // B2: Sb reads done before next rt overwrites
    }

    // ---- pre-projection activations -> preB ----
#pragma unroll
    for (int mt = 0; mt < 4; ++mt)
#pragma unroll
      for (int nt = 0; nt < 2; ++nt)
#pragma unroll
        for (int r = 0; r < 4; ++r)
          preB[(mt * 16 + quad * 4 + r) * 264 + h * 32 + nt * 16 + m] = (f16)oacc[mt][nt][r];
    __syncthreads();   // preB ready

    // ---- proj GEMM from preB (f16 weights) ----
    const f16* __restrict__ Wp = view ? pw2 : pw1;
    const float* __restrict__ pb = view ? pb2 : pb1;
    f32x4 pacc0[4], pacc1[4];
#pragma unroll
    for (int t = 0; t < 4; ++t) { pacc0[t] = z4; pacc1[t] = z4; }
#pragma unroll 2
    for (int ks = 0; ks < 8; ++ks) {
      f16x8 pa0 = *(const f16x8*)(Wp + (size_t)(h * 32 + m) * 256 + ks * 32 + quad * 8);
      f16x8 pa1 = *(const f16x8*)(Wp + (size_t)(h * 32 + 16 + m) * 256 + ks * 32 + quad * 8);
#pragma unroll
      for (int tt = 0; tt < 4; ++tt) {
        f16x8 bfr = *(const f16x8*)(preB + (tt * 16 + m) * 264 + ks * 32 + quad * 8);
        pacc0[tt] = MFMA_F16(pa0, bfr, pacc0[tt]);
        pacc1[tt] = MFMA_F16(pa1, bfr, pacc1[tt]);
      }
    }
    // ---- FP32 output store ----
    float* obase = outp + (size_t)(view * NWIN + win) * (64 * 256);
#pragma unroll
    for (int tt = 0; tt < 4; ++tt) {
      f32x4 p0, p1;
#pragma unroll
      for (int r = 0; r < 4; ++r) {
        p0[r] = pacc0[tt][r] + pb[h * 32 + quad * 4 + r];
        p1[r] = pacc1[tt][r] + pb[h * 32 + 16 + quad * 4 + r];
      }
      const int n = tt * 16 + m;
      *(f32x4*)(obase + n * 256 + h * 32 + quad * 4)      = p0;
      *(f32x4*)(obase + n * 256 + h * 32 + 16 + quad * 4) = p1;
    }
    __syncthreads();   // preB/Sb reads done before next view reuses sm
  }
}

extern "C" void kernel_launch(void* const* d_in, const int* in_sizes, int n_in,
                              void* d_out, int out_size, void* d_ws, size_t ws_size,
                              hipStream_t stream) {
  (void)in_sizes; (void)n_in; (void)out_size; (void)ws_size;
  const float* x1   = (const float*)d_in[0];
  const float* x2   = (const float*)d_in[1];
  const float* qkvw1= (const float*)d_in[2];
  const float* qb1  = (const float*)d_in[3];
  const float* vb1  = (const float*)d_in[4];
  const float* pw1  = (const float*)d_in[5];
  const float* pb1  = (const float*)d_in[6];
  const float* ls1  = (const float*)d_in[7];
  const float* cw11 = (const float*)d_in[8];
  const float* cb11 = (const float*)d_in[9];
  const float* cw12 = (const float*)d_in[10];
  const float* pcw1 = (const float*)d_in[11];
  const float* pcb1 = (const float*)d_in[12];
  const float* qkvw2= (const float*)d_in[13];
  const float* qb2  = (const float*)d_in[14];
  const float* vb2  = (const float*)d_in[15];
  const float* pw2  = (const float*)d_in[16];
  const float* pb2  = (const float*)d_in[17];
  const float* ls2  = (const float*)d_in[18];
  const float* cw21 = (const float*)d_in[19];
  const float* cb21 = (const float*)d_in[20];
  const float* cw22 = (const float*)d_in[21];
  const float* pcw2 = (const float*)d_in[22];
  const float* pcb2 = (const float*)d_in[23];

  // workspace: sg16 [2][225][8] f32 (14400 B) | qkvw1 f16 | qkvw2 f16 |
  // pw1 f16 | pw2 f16  -> ~1.04 MB
  float* SG16 = (float*)d_ws;
  f16* wq1f = (f16*)((char*)d_ws + 14400);
  f16* wq2f = wq1f + 196608;
  f16* pw1f = wq2f + 196608;
  f16* pw2f = pw1f + 65536;
  float* out = (float*)d_out;

  prep_all<<<706, 256, 0, stream>>>(cw11, cb11, cw12, cw21, cb21, cw22,
                                    qkvw1, qkvw2, pw1, pw2,
                                    SG16, wq1f, wq2f, pw1f, pw2f);
  fused_attn<<<NWIN, 512, 0, stream>>>(x1, x2,
      wq1f, qb1, vb1, wq2f, qb2, vb2,
      pcw1, pcb1, ls1, pcw2, pcb2, ls2,
      pw1f, pb1, pw2f, pb2, SG16, out);
}

// Round 8
// 273.648 us; speedup vs baseline: 1.7554x; 1.0156x over previous
//
#include <hip/hip_runtime.h>

typedef _Float16 f16;
typedef f16  f16x8  __attribute__((ext_vector_type(8)));
typedef f16  f16x4v __attribute__((ext_vector_type(4)));
typedef f16  f16x2  __attribute__((ext_vector_type(2)));
typedef float f32x4 __attribute__((ext_vector_type(4)));

#define MFMA_F16(a,b,c) __builtin_amdgcn_mfma_f32_16x16x32_f16((a),(b),(c),0,0,0)

#define NWIN 512
// Sb: [16 qrows][64 k][8 dwords + 16B pad] — each dword = f16x2 (same,diff)
// score pair for one head. Row stride 3088 B (≡16 mod 128 so b128 reads
// spread m&7 over 8 slots; 48 B k-slot spreads writes). NO XOR swizzle
// (R4/R5's XOR collided: rows not 128-aligned).
#define SB_QST 3088
#define SB_KST 48
// full-x staging: [64 tok][256 + 8 pad] f16 (528 B row)
#define BUFX_ST 264
// per-head QKV output scratch: Q/K swizzled [64][32] (4096 B), V transposed [32][72]
#define BUFO_HEAD 2304
#define VT_ST 72
// sm layout: bufX [0,33792) | bufO [33792,70656)
// attention reuse: Sb [0,49408) | sTbl [49408,65608)
// sTbl row stride = 9 floats (was 8): bank = (9*idx + h) mod 32 spreads the
// per-wave gather (h fixed per wave) over all banks; stride 8 pinned the
// whole wave to 4 banks -> ~16-way serialization on 128 lookups/wave,
// est ~30K conflict cycles/CU — the largest single conflict source.
#define STBL_STRIDE 9
#define SM_BYTES 70656
#define STBL_OFF 49408

// load 8 consecutive fp32, round to f16x8
__device__ __forceinline__ f16x8 ld_f16x8(const float* __restrict__ p) {
  f32x4 a = *(const f32x4*)p;
  f32x4 b = *(const f32x4*)(p + 4);
  f16x8 r;
  r[0] = (f16)a[0]; r[1] = (f16)a[1]; r[2] = (f16)a[2]; r[3] = (f16)a[3];
  r[4] = (f16)b[0]; r[5] = (f16)b[1]; r[6] = (f16)b[2]; r[7] = (f16)b[3];
  return r;
}

// ---------------- prep: CPB MLP table + weight f32->f16 conversion ----------
__global__ __launch_bounds__(256) void prep_all(
    const float* __restrict__ w1a, const float* __restrict__ b1a,
    const float* __restrict__ w2a,
    const float* __restrict__ w1b, const float* __restrict__ b1b,
    const float* __restrict__ w2b,
    const float* __restrict__ qkvw1, const float* __restrict__ qkvw2,
    const float* __restrict__ pw1, const float* __restrict__ pw2,
    float* __restrict__ sg16,
    f16* __restrict__ wq1f, f16* __restrict__ wq2f,
    f16* __restrict__ pw1f, f16* __restrict__ pw2f) {
  const int b = blockIdx.x;
  if (b >= 450) {
    const int cb = b - 450;
    const float* src; f16* dst; int base;
    if (cb < 96)       { src = qkvw1; dst = wq1f; base = cb * 2048; }
    else if (cb < 192) { src = qkvw2; dst = wq2f; base = (cb - 96) * 2048; }
    else if (cb < 224) { src = pw1;   dst = pw1f; base = (cb - 192) * 2048; }
    else               { src = pw2;   dst = pw2f; base = (cb - 224) * 2048; }
    const int o = base + threadIdx.x * 8;
    *(f16x8*)(dst + o) = ld_f16x8(src + o);
    return;
  }
  const int view = b / 225;
  const int e    = b % 225;
  const float* __restrict__ w1 = view ? w1b : w1a;
  const float* __restrict__ b1 = view ? b1b : b1a;
  const float* __restrict__ w2 = view ? w2b : w2a;
  const int t = threadIdx.x;
  const int i = e / 15, j = e % 15;
  const float vi = 8.0f * (float)(i - 7) * (1.0f / 7.0f);
  const float vj = 8.0f * (float)(j - 7) * (1.0f / 7.0f);
  const float in0 = copysignf(log2f(fabsf(vi) + 1.0f) * (1.0f / 3.0f), vi);
  const float in1 = copysignf(log2f(fabsf(vj) + 1.0f) * (1.0f / 3.0f), vj);
  float acc[8] = {0.f,0.f,0.f,0.f,0.f,0.f,0.f,0.f};
#pragma unroll
  for (int uu = 0; uu < 2; ++uu) {
    const int u = t + uu * 256;
    float hv = fmaxf(w1[2*u] * in0 + w1[2*u+1] * in1 + b1[u], 0.0f);
#pragma unroll
    for (int hh = 0; hh < 8; ++hh) acc[hh] += w2[hh*512 + u] * hv;
  }
#pragma unroll
  for (int off = 32; off >= 1; off >>= 1)
#pragma unroll
    for (int hh = 0; hh < 8; ++hh) acc[hh] += __shfl_xor(acc[hh], off, 64);
  __shared__ float red[4][8];
  if ((t & 63) == 0) {
#pragma unroll
    for (int hh = 0; hh < 8; ++hh) red[t >> 6][hh] = acc[hh];
  }
  __syncthreads();
  if (t < 8) {
    float s = red[0][t] + red[1][t] + red[2][t] + red[3][t];
    sg16[(view * 225 + e) * 8 + t] = 16.0f / (1.0f + __expf(-s));
  }
}

// ---------------- fused: per-window (both views) QKV + attention + proj ------
// launch_bounds (512, 2): LDS caps at 2 blocks/CU; asking 4 (R2) forced
// VGPR=64 -> ~350 MB scratch spill. 2 -> 128 VGPR, no spill.
__global__ __launch_bounds__(512, 2) void fused_attn(
    const float* __restrict__ x1, const float* __restrict__ x2,
    const f16* __restrict__ qkvw1, const float* __restrict__ qb1, const float* __restrict__ vb1,
    const f16* __restrict__ qkvw2, const float* __restrict__ qb2, const float* __restrict__ vb2,
    const float* __restrict__ pcw1, const float* __restrict__ pcb1, const float* __restrict__ ls1,
    const float* __restrict__ pcw2, const float* __restrict__ pcb2, const float* __restrict__ ls2,
    const f16* __restrict__ pw1, const float* __restrict__ pb1,
    const f16* __restrict__ pw2, const float* __restrict__ pb2,
    const float* __restrict__ sg16,
    float* __restrict__ outp) {
  const int win = blockIdx.x;
  const int tid = threadIdx.x;
  const int lane = tid & 63, h = tid >> 6;
  const int quad = lane >> 4, m = lane & 15;

  __shared__ __align__(16) char sm[SM_BYTES];
  f16* bufX  = (f16*)sm;
  f16* bufO  = (f16*)(sm + 33792);
  char* Sbc  = sm;                    // Sb accessed via byte addresses
  f16* preB  = (f16*)sm;
  float* sTbl = (float*)(sm + STBL_OFF);

  const f32x4 z4 = {0.f, 0.f, 0.f, 0.f};
  f16x8 aqF[2][4], kfF[2][4], bvF[2][2][2];
  f16* oh = bufO + h * BUFO_HEAD;

  // ================= QKV GEMMs, both views =================
  for (int view = 0; view < 2; ++view) {
    const float* __restrict__ xv = (view ? x2 : x1) + (size_t)win * (64 * 256);
    const f16* __restrict__ W    = view ? qkvw2 : qkvw1;
    const float* __restrict__ qb = view ? qb2 : qb1;
    const float* __restrict__ vb = view ? vb2 : vb1;

    __syncthreads();   // bufX/bufO safe to overwrite (prev view's reads done)
    for (int i = tid; i < 2048; i += 512) {           // 64 rows x 32 chunks of 8
      const int row = i >> 5, c8 = i & 31;
      *(f16x8*)(bufX + row * BUFX_ST + c8 * 8) = ld_f16x8(xv + row * 256 + c8 * 8);
    }
    __syncthreads();   // bufX ready (stable for all 3 secs)

    for (int sec = 0; sec < 3; ++sec) {
      f32x4 acc0[4], acc1[4];
#pragma unroll
      for (int t = 0; t < 4; ++t) { acc0[t] = z4; acc1[t] = z4; }
      const f16* wb = W + (size_t)(sec * 256 + h * 32) * 256 + quad * 8;
      __builtin_amdgcn_s_setprio(1);
#pragma unroll 2
      for (int k8 = 0; k8 < 8; ++k8) {
        f16x8 a0 = *(const f16x8*)(wb + (size_t)m * 256 + k8 * 32);
        f16x8 a1 = *(const f16x8*)(wb + (size_t)(16 + m) * 256 + k8 * 32);
#pragma unroll
        for (int tt = 0; tt < 4; ++tt) {
          f16x8 bfr = *(const f16x8*)(bufX + (tt * 16 + m) * BUFX_ST + k8 * 32 + quad * 8);
          acc0[tt] = MFMA_F16(a0, bfr, acc0[tt]);
          acc1[tt] = MFMA_F16(a1, bfr, acc1[tt]);
        }
      }
      __builtin_amdgcn_s_setprio(0);
      // epilogue: bias, (l2norm q/k), write to own head's bufO region.
      float bs0[4], bs1[4];
#pragma unroll
      for (int r = 0; r < 4; ++r) {
        int c0 = h * 32 + quad * 4 + r;
        bs0[r] = (sec == 0) ? qb[c0] : (sec == 2 ? vb[c0] : 0.f);
        bs1[r] = (sec == 0) ? qb[c0 + 16] : (sec == 2 ? vb[c0 + 16] : 0.f);
      }
#pragma unroll
      for (int tt = 0; tt < 4; ++tt) {
        float v0[4], v1[4];
#pragma unroll
        for (int r = 0; r < 4; ++r) { v0[r] = acc0[tt][r] + bs0[r]; v1[r] = acc1[tt][r] + bs1[r]; }
        if (sec < 2) {
          float ss = 0.f;
#pragma unroll
          for (int r = 0; r < 4; ++r) ss += v0[r] * v0[r] + v1[r] * v1[r];
          ss += __shfl_xor(ss, 16, 64);
          ss += __shfl_xor(ss, 32, 64);
          float s = 1.0f / fmaxf(sqrtf(ss), 1e-12f);
#pragma unroll
          for (int r = 0; r < 4; ++r) { v0[r] *= s; v1[r] *= s; }
        }
        const int n = tt * 16 + m;
        if (sec < 2) {
          // Q/K: swizzled [tok][32ch] layout (bijective within 64B rows)
          f16x4v p0, p1;
#pragma unroll
          for (int r = 0; r < 4; ++r) { p0[r] = (f16)v0[r]; p1[r] = (f16)v1[r]; }
          char* ob = (char*)oh;
          const int sw = (n & 7) << 4;
          *(f16x4v*)(ob + ((n * 64 + quad * 8) ^ sw))      = p0;
          *(f16x4v*)(ob + ((n * 64 + 32 + quad * 8) ^ sw)) = p1;
        } else {
          // V: store transposed Vt[ch][tok] so fragment reads are vector loads
#pragma unroll
          for (int r = 0; r < 4; ++r) {
            oh[(quad * 4 + r) * VT_ST + n]      = (f16)v0[r];
            oh[(quad * 4 + 16 + r) * VT_ST + n] = (f16)v1[r];
          }
        }
      }
      // fragment extraction — own-head region only, no barrier needed
      if (sec == 0) {
#pragma unroll
        for (int rt = 0; rt < 4; ++rt) {
          const int n = rt * 16 + m;
          aqF[view][rt] = *(const f16x8*)((char*)oh + ((n * 64 + quad * 16) ^ ((n & 7) << 4)));
        }
      } else if (sec == 1) {
#pragma unroll
        for (int ct = 0; ct < 4; ++ct) {
          const int n = ct * 16 + m;
          kfF[view][ct] = *(const f16x8*)((char*)oh + ((n * 64 + quad * 16) ^ ((n & 7) << 4)));
        }
      } else {
#pragma unroll
        for (int nt = 0; nt < 2; ++nt)
#pragma unroll
          for (int kv = 0; kv < 2; ++kv)
            bvF[view][nt][kv] = *(const f16x8*)(oh + (nt * 16 + m) * VT_ST + kv * 32 + quad * 8);
      }
    }
  }
  __syncthreads();   // all fragments in regs; sm free for Sb/sTbl

  // load bias table once for BOTH views; store with row stride 9 (bank spread)
  for (int i = tid; i < 3600; i += 512)
    sTbl[(i >> 3) * STBL_STRIDE + (i & 7)] = sg16[i];

  // ================= attention + proj, both views =================
#pragma unroll
  for (int view = 0; view < 2; ++view) {
    const float* __restrict__ pcw = view ? pcw2 : pcw1;
    // fdot2 weight pairs matched to Sb's (same,diff) dword packing.
    f16x2 w0[4], w1[4];
#pragma unroll
    for (int c = 0; c < 4; ++c) {
      f16x2 a, b;
      a[0] = (f16)pcw[h * 16 + c];     a[1] = (f16)pcw[h * 16 + 8 + c];
      b[0] = (f16)pcw[h * 16 + 4 + c]; b[1] = (f16)pcw[h * 16 + 12 + c];
      w0[c] = a; w1[c] = b;
    }
    const float pcb_h = (view ? pcb2 : pcb1)[h];
    const float lsv = (view ? ls2 : ls1)[h];
    const float scale_h = __expf(fminf(lsv, 4.6051702f));
    const float pcbs = pcb_h * scale_h;
    const float* tblv = sTbl + view * (225 * STBL_STRIDE);

    f32x4 oacc[4][2];
#pragma unroll
    for (int rt = 0; rt < 4; ++rt) {
      f16x8 aq = aqF[view][rt];
      // Score MFMAs; pack (same,diff) per head into one dword -> ds_write_b32.
      __builtin_amdgcn_s_setprio(1);
#pragma unroll
      for (int ct = 0; ct < 4; ++ct) {
        const int kk = ct * 16 + m;
        const int wbase = kk * SB_KST + (h << 2);
        f32x4 Ss = MFMA_F16(aq, kfF[view][ct], z4);
        f32x4 Sd = MFMA_F16(aq, kfF[1 - view][ct], z4);
#pragma unroll
        for (int r = 0; r < 4; ++r) {
          f16x2 pr; pr[0] = (f16)Ss[r]; pr[1] = (f16)Sd[r];
          *(f16x2*)(Sbc + (quad * 4 + r) * SB_QST + wbase) = pr;
        }
      }
      __builtin_amdgcn_s_setprio(0);
      __syncthreads();   // B1: Sb complete (all heads' channels)

      // ---- logits: 16-ch mix via v_dot2_f32_f16; softmax; AV ----
      const int n = rt * 16 + m;
      const int nh_ = n >> 3, nw_ = n & 7;
      const int rbase = m * SB_QST;
      float logit[16];
#pragma unroll
      for (int j = 0; j < 16; ++j) {
        const int mm = (j < 8) ? (quad * 8 + j) : (32 + quad * 8 + (j - 8));
        const int b0 = rbase + mm * SB_KST;
        f16x8 s0 = *(const f16x8*)(Sbc + b0);        // heads 0-3: (s,d) pairs
        f16x8 s1 = *(const f16x8*)(Sbc + b0 + 16);   // heads 4-7
        const f16x2* s0p = (const f16x2*)&s0;
        const f16x2* s1p = (const f16x2*)&s1;
        float mix = 0.f;
#pragma unroll
        for (int c = 0; c < 4; ++c) {
          mix = __builtin_amdgcn_fdot2(s0p[c], w0[c], mix, false);
          mix = __builtin_amdgcn_fdot2(s1p[c], w1[c], mix, false);
        }
        const int idx = (nh_ - (mm >> 3) + 7) * 15 + (nw_ - (mm & 7) + 7);
        logit[j] = mix * scale_h + pcbs + tblv[idx * STBL_STRIDE + h];
      }
      float mx = -1e30f;
#pragma unroll
      for (int j = 0; j < 16; ++j) mx = fmaxf(mx, logit[j]);
      mx = fmaxf(mx, __shfl_xor(mx, 16, 64));
      mx = fmaxf(mx, __shfl_xor(mx, 32, 64));
      float p[16], sum = 0.f;
#pragma unroll
      for (int j = 0; j < 16; ++j) { p[j] = __expf(logit[j] - mx); sum += p[j]; }
      sum += __shfl_xor(sum, 16, 64);
      sum += __shfl_xor(sum, 32, 64);
      float inv = 1.0f / sum;
      f16x8 av0, av1;
#pragma unroll
      for (int j = 0; j < 8; ++j) { av0[j] = (f16)(p[j] * inv); av1[j] = (f16)(p[8 + j] * inv); }
      __builtin_amdgcn_s_setprio(1);
#pragma unroll
      for (int nt = 0; nt < 2; ++nt) {
        f32x4 z = z4;
        z = MFMA_F16(av0, bvF[view][nt][0], z);
        z = MFMA_F16(av1, bvF[view][nt][1], z);
        oacc[rt][nt] = z;
      }
      __builtin_amdgcn_s_setprio(0);
      __syncthreads();   // B2: Sb reads done before next rt overwrites
    }

    // ---- pre-projection activations -> preB ----
#pragma unroll
    for (int mt = 0; mt < 4; ++mt)
#pragma unroll
      for (int nt = 0; nt < 2; ++nt)
#pragma unroll
        for (int r = 0; r < 4; ++r)
          preB[(mt * 16 + quad * 4 + r) * 264 + h * 32 + nt * 16 + m] = (f16)oacc[mt][nt][r];
    __syncthreads();   // preB ready

    // ---- proj GEMM from preB (f16 weights) ----
    const f16* __restrict__ Wp = view ? pw2 : pw1;
    const float* __restrict__ pb = view ? pb2 : pb1;
    f32x4 pacc0[4], pacc1[4];
#pragma unroll
    for (int t = 0; t < 4; ++t) { pacc0[t] = z4; pacc1[t] = z4; }
    __builtin_amdgcn_s_setprio(1);
#pragma unroll 2
    for (int ks = 0; ks < 8; ++ks) {
      f16x8 pa0 = *(const f16x8*)(Wp + (size_t)(h * 32 + m) * 256 + ks * 32 + quad * 8);
      f16x8 pa1 = *(const f16x8*)(Wp + (size_t)(h * 32 + 16 + m) * 256 + ks * 32 + quad * 8);
#pragma unroll
      for (int tt = 0; tt < 4; ++tt) {
        f16x8 bfr = *(const f16x8*)(preB + (tt * 16 + m) * 264 + ks * 32 + quad * 8);
        pacc0[tt] = MFMA_F16(pa0, bfr, pacc0[tt]);
        pacc1[tt] = MFMA_F16(pa1, bfr, pacc1[tt]);
      }
    }
    __builtin_amdgcn_s_setprio(0);
    // ---- FP32 output store ----
    float* obase = outp + (size_t)(view * NWIN + win) * (64 * 256);
#pragma unroll
    for (int tt = 0; tt < 4; ++tt) {
      f32x4 p0, p1;
#pragma unroll
      for (int r = 0; r < 4; ++r) {
        p0[r] = pacc0[tt][r] + pb[h * 32 + quad * 4 + r];
        p1[r] = pacc1[tt][r] + pb[h * 32 + 16 + quad * 4 + r];
      }
      const int n = tt * 16 + m;
      *(f32x4*)(obase + n * 256 + h * 32 + quad * 4)      = p0;
      *(f32x4*)(obase + n * 256 + h * 32 + 16 + quad * 4) = p1;
    }
    __syncthreads();   // preB/Sb reads done before next view reuses sm
  }
}

extern "C" void kernel_launch(void* const* d_in, const int* in_sizes, int n_in,
                              void* d_out, int out_size, void* d_ws, size_t ws_size,
                              hipStream_t stream) {
  (void)in_sizes; (void)n_in; (void)out_size; (void)ws_size;
  const float* x1   = (const float*)d_in[0];
  const float* x2   = (const float*)d_in[1];
  const float* qkvw1= (const float*)d_in[2];
  const float* qb1  = (const float*)d_in[3];
  const float* vb1  = (const float*)d_in[4];
  const float* pw1  = (const float*)d_in[5];
  const float* pb1  = (const float*)d_in[6];
  const float* ls1  = (const float*)d_in[7];
  const float* cw11 = (const float*)d_in[8];
  const float* cb11 = (const float*)d_in[9];
  const float* cw12 = (const float*)d_in[10];
  const float* pcw1 = (const float*)d_in[11];
  const float* pcb1 = (const float*)d_in[12];
  const float* qkvw2= (const float*)d_in[13];
  const float* qb2  = (const float*)d_in[14];
  const float* vb2  = (const float*)d_in[15];
  const float* pw2  = (const float*)d_in[16];
  const float* pb2  = (const float*)d_in[17];
  const float* ls2  = (const float*)d_in[18];
  const float* cw21 = (const float*)d_in[19];
  const float* cb21 = (const float*)d_in[20];
  const float* cw22 = (const float*)d_in[21];
  const float* pcw2 = (const float*)d_in[22];
  const float* pcb2 = (const float*)d_in[23];

  // workspace: sg16 [2][225][8] f32 (14400 B) | qkvw1 f16 | qkvw2 f16 |
  // pw1 f16 | pw2 f16  -> ~1.04 MB
  float* SG16 = (float*)d_ws;
  f16* wq1f = (f16*)((char*)d_ws + 14400);
  f16* wq2f = wq1f + 196608;
  f16* pw1f = wq2f + 196608;
  f16* pw2f = pw1f + 65536;
  float* out = (float*)d_out;

  prep_all<<<706, 256, 0, stream>>>(cw11, cb11, cw12, cw21, cb21, cw22,
                                    qkvw1, qkvw2, pw1, pw2,
                                    SG16, wq1f, wq2f, pw1f, pw2f);
  fused_attn<<<NWIN, 512, 0, stream>>>(x1, x2,
      wq1f, qb1, vb1, wq2f, qb2, vb2,
      pcw1, pcb1, ls1, pcw2, pcb2, ls2,
      pw1f, pb1, pw2f, pb2, SG16, out);
}